// Round 2
// baseline (365.954 us; speedup 1.0000x reference)
//
#include <hip/hip_runtime.h>
#include <hip/hip_bf16.h>

typedef __attribute__((ext_vector_type(8))) short bf16x8;
typedef __attribute__((ext_vector_type(4))) float f32x4;

#define MFMA16x16x32(a, b, c) __builtin_amdgcn_mfma_f32_16x16x32_bf16(a, b, c, 0, 0, 0)

#define LOG2E 1.44269504f
#define QSCALE (0.125f * 1.44269504f)

__device__ __forceinline__ unsigned short f2b(float x) {
    union { float f; unsigned int u; } v; v.f = x;
    unsigned int r = v.u + 0x7FFFu + ((v.u >> 16) & 1u);
    return (unsigned short)(r >> 16);
}

__device__ __forceinline__ void gload_lds16(const unsigned short* g, unsigned short* l) {
    __builtin_amdgcn_global_load_lds((const __attribute__((address_space(1))) void*)g,
                                     (__attribute__((address_space(3))) void*)l, 16, 0, 0);
}

// ---------------- fp32 -> bf16 convert (hidden states) ----------------
__global__ __launch_bounds__(256) void cvt_bf16_kernel(const float* __restrict__ in,
                                                       unsigned short* __restrict__ out, int n) {
    int i = (blockIdx.x * 256 + threadIdx.x) * 4;
    if (i >= n) return;
    float4 v = *reinterpret_cast<const float4*>(in + i);
    ushort4 o;
    o.x = f2b(v.x); o.y = f2b(v.y); o.z = f2b(v.z); o.w = f2b(v.w);
    *reinterpret_cast<ushort4*>(out + i) = o;
}

// ---------------- W [K][N] fp32 -> WT [N][K] bf16 (tiled transpose) ----------------
__global__ __launch_bounds__(256) void transpose_cvt_kernel(const float* __restrict__ Wq,
                                                            const float* __restrict__ Wk,
                                                            const float* __restrict__ Wv,
                                                            unsigned short* __restrict__ WTall) {
    int z = blockIdx.z;
    const float* in = (z == 0) ? Wq : (z == 1) ? Wk : Wv;
    unsigned short* outp = WTall + (size_t)z * 1024 * 1024;
    __shared__ float tile[32][33];
    int tx = threadIdx.x, ty = threadIdx.y;
    int x = blockIdx.x * 32 + tx;
    int y0 = blockIdx.y * 32;
    #pragma unroll
    for (int j = ty; j < 32; j += 8)
        tile[j][tx] = in[(size_t)(y0 + j) * 1024 + x];
    __syncthreads();
    int ox = y0 + tx;
    int oy0 = blockIdx.x * 32;
    #pragma unroll
    for (int j = ty; j < 32; j += 8)
        outp[(size_t)(oy0 + j) * 1024 + ox] = f2b(tile[tx][j]);
}

// ---------------- T5 bias LUT (pre-scaled by log2e): bt[h][n], n = max(q-k,0) ----------------
__global__ __launch_bounds__(256) void build_bt_kernel(const float* __restrict__ rel_bias,
                                                       float* __restrict__ bt) {
    int n = blockIdx.x * 256 + threadIdx.x;
    if (n >= 2048) return;
    int bucket;
    if (n < 16) {
        bucket = n;
    } else {
        float nf = (float)n;
        int v = 16 + (int)((logf(nf / 16.0f) / 0.69314718f) * 16.0f);
        bucket = v < 31 ? v : 31;
    }
    #pragma unroll
    for (int h = 0; h < 16; ++h)
        bt[(size_t)h * 2048 + n] = rel_bias[bucket * 16 + h] * LOG2E;
}

// ---------------- QKV projection GEMM (m97 structure: global_load_lds w=16) ----------------
// A [4096][1024] bf16; WT [N][K] bf16. z=0 -> q (scaled by QSCALE), z=1 -> k, z=2 -> v transposed
// per head: vt[((b*16+h)*64+d)][s].
__global__ __launch_bounds__(256) void gemm_qkv_kernel(const unsigned short* __restrict__ A,
                                                       const unsigned short* __restrict__ WTall,
                                                       const float* __restrict__ bq,
                                                       const float* __restrict__ bk,
                                                       const float* __restrict__ bv,
                                                       unsigned short* __restrict__ qws,
                                                       unsigned short* __restrict__ kws,
                                                       unsigned short* __restrict__ vtw) {
    const int K = 1024;
    int z = blockIdx.z;
    const unsigned short* Bm = WTall + (size_t)z * 1024 * 1024;
    const float* bias = (z == 0) ? bq : (z == 1) ? bk : bv;

    __shared__ unsigned short As[128 * 32];   // linear [row][32k] for global_load_lds
    __shared__ unsigned short Bs[128 * 32];

    int t = threadIdx.x;
    int lane = t & 63, w = t >> 6;
    int wr = w >> 1, wc = w & 1;
    int g = lane >> 4, r = lane & 15;
    int m0 = blockIdx.x * 128, n0 = blockIdx.y * 128;

    // staging addresses: wave w stages rows [w*32, w*32+31] of each tile
    int lrow = lane >> 2;
    int lcol = (lane & 3) * 8;
    const unsigned short* ga0 = A + (size_t)(m0 + w * 32 + lrow) * K + lcol;
    const unsigned short* ga1 = ga0 + 16 * K;
    const unsigned short* gb0 = Bm + (size_t)(n0 + w * 32 + lrow) * K + lcol;
    const unsigned short* gb1 = gb0 + 16 * K;
    unsigned short* lA0 = &As[(w * 32) * 32];
    unsigned short* lA1 = &As[(w * 32 + 16) * 32];
    unsigned short* lB0 = &Bs[(w * 32) * 32];
    unsigned short* lB1 = &Bs[(w * 32 + 16) * 32];

    f32x4 acc[4][4] = {};

    for (int kb = 0; kb < K; kb += 32) {
        gload_lds16(ga0 + kb, lA0);
        gload_lds16(ga1 + kb, lA1);
        gload_lds16(gb0 + kb, lB0);
        gload_lds16(gb1 + kb, lB1);
        __syncthreads();

        bf16x8 af[4], bfr[4];
        #pragma unroll
        for (int i = 0; i < 4; ++i)
            af[i] = *reinterpret_cast<const bf16x8*>(&As[(wr * 64 + i * 16 + r) * 32 + g * 8]);
        #pragma unroll
        for (int j = 0; j < 4; ++j)
            bfr[j] = *reinterpret_cast<const bf16x8*>(&Bs[(wc * 64 + j * 16 + r) * 32 + g * 8]);
        #pragma unroll
        for (int i = 0; i < 4; ++i) {
            #pragma unroll
            for (int j = 0; j < 4; ++j)
                acc[i][j] = MFMA16x16x32(af[i], bfr[j], acc[i][j]);
        }
        __syncthreads();
    }

    if (z < 2) {
        unsigned short* C = (z == 0) ? qws : kws;
        float sc = (z == 0) ? QSCALE : 1.0f;
        #pragma unroll
        for (int j = 0; j < 4; ++j) {
            int n = n0 + wc * 64 + j * 16 + r;
            float bj = bias[n];
            #pragma unroll
            for (int i = 0; i < 4; ++i) {
                int mbase = m0 + wr * 64 + i * 16 + g * 4;
                #pragma unroll
                for (int e = 0; e < 4; ++e)
                    C[(size_t)(mbase + e) * 1024 + n] = f2b((acc[i][j][e] + bj) * sc);
            }
        }
    } else {
        #pragma unroll
        for (int j = 0; j < 4; ++j) {
            int n = n0 + wc * 64 + j * 16 + r;
            int hh = n >> 6, d = n & 63;
            float bj = bias[n];
            #pragma unroll
            for (int i = 0; i < 4; ++i) {
                int mbase = m0 + wr * 64 + i * 16 + g * 4;
                int bb = mbase >> 11, s = mbase & 2047;
                ushort4 pk4;
                pk4.x = f2b(acc[i][j][0] + bj);
                pk4.y = f2b(acc[i][j][1] + bj);
                pk4.z = f2b(acc[i][j][2] + bj);
                pk4.w = f2b(acc[i][j][3] + bj);
                *reinterpret_cast<ushort4*>(vtw + ((size_t)((bb * 16 + hh) * 64 + d)) * 2048 + s) = pk4;
            }
        }
    }
}

// ---------------- Flash attention, no K/V staging (L2-resident), KBLK=64 ----------------
// 1-D grid of 1024 blocks; XCD swizzle: bh = (p&7) | ((p>>8)<<3), qt = (p>>3)&31
// so all 32 q-tiles of a head share one XCD's L2 (4 heads x 768KB = 3MB per L2).
__global__ __launch_bounds__(256) void attn_kernel(const unsigned short* __restrict__ qg,
                                                   const unsigned short* __restrict__ kg,
                                                   const unsigned short* __restrict__ vt,
                                                   const float* __restrict__ bt,
                                                   float* __restrict__ out) {
    int p = blockIdx.x;
    int bh = (p & 7) | ((p >> 8) << 3);
    int qt = (p >> 3) & 31;
    int b = bh >> 4, h = bh & 15;
    int t = threadIdx.x;
    int lane = t & 63, w = t >> 6;
    int g = lane >> 4, r = lane & 15;

    __shared__ float bts[2048];
    __shared__ unsigned short Ps[4][16][68];   // per-wave P tile [q=r][64 keys], +4 pad

    for (int i = t; i < 2048; i += 256) bts[i] = bt[(size_t)h * 2048 + i];
    __syncthreads();

    int qrow = qt * 64 + w * 16 + r;
    const unsigned short* qptr = qg + ((size_t)(b * 2048 + qrow)) * 1024 + h * 64;
    bf16x8 qf0 = *reinterpret_cast<const bf16x8*>(qptr + g * 8);
    bf16x8 qf1 = *reinterpret_cast<const bf16x8*>(qptr + 32 + g * 8);

    // K fragment pointers: A-operand rows kv + kt*16 + r, cols d = g*8 (+32)
    const unsigned short* kp0 = kg + ((size_t)(b * 2048 + 0 * 16 + r)) * 1024 + h * 64 + g * 8;
    const unsigned short* kp1 = kg + ((size_t)(b * 2048 + 1 * 16 + r)) * 1024 + h * 64 + g * 8;
    const unsigned short* kp2 = kg + ((size_t)(b * 2048 + 2 * 16 + r)) * 1024 + h * 64 + g * 8;
    const unsigned short* kp3 = kg + ((size_t)(b * 2048 + 3 * 16 + r)) * 1024 + h * 64 + g * 8;
    // V^T fragment pointers: B-operand row d = nt*16 + r, cols key = kv + c*32 + g*8
    const unsigned short* vp0 = vt + ((size_t)((b * 16 + h) * 64 + 0 * 16 + r)) * 2048 + g * 8;
    const unsigned short* vp1 = vt + ((size_t)((b * 16 + h) * 64 + 1 * 16 + r)) * 2048 + g * 8;
    const unsigned short* vp2 = vt + ((size_t)((b * 16 + h) * 64 + 2 * 16 + r)) * 2048 + g * 8;
    const unsigned short* vp3 = vt + ((size_t)((b * 16 + h) * 64 + 3 * 16 + r)) * 2048 + g * 8;

    float mrun = -1e30f, lrun = 0.f;
    f32x4 o[4] = {};   // o[nt][e]: q = g*4+e, d = nt*16 + r

    for (int kv = 0; kv < 2048; kv += 64) {
        // ---- QK^T (swapped): lane holds S[q=r][key = kv + kt*16 + g*4 + e] ----
        f32x4 sc[4];
        {
            bf16x8 ka, kb2;
            ka = *reinterpret_cast<const bf16x8*>(kp0);
            kb2 = *reinterpret_cast<const bf16x8*>(kp0 + 32);
            f32x4 s0 = {}; s0 = MFMA16x16x32(ka, qf0, s0); sc[0] = MFMA16x16x32(kb2, qf1, s0);
            ka = *reinterpret_cast<const bf16x8*>(kp1);
            kb2 = *reinterpret_cast<const bf16x8*>(kp1 + 32);
            f32x4 s1 = {}; s1 = MFMA16x16x32(ka, qf0, s1); sc[1] = MFMA16x16x32(kb2, qf1, s1);
            ka = *reinterpret_cast<const bf16x8*>(kp2);
            kb2 = *reinterpret_cast<const bf16x8*>(kp2 + 32);
            f32x4 s2 = {}; s2 = MFMA16x16x32(ka, qf0, s2); sc[2] = MFMA16x16x32(kb2, qf1, s2);
            ka = *reinterpret_cast<const bf16x8*>(kp3);
            kb2 = *reinterpret_cast<const bf16x8*>(kp3 + 32);
            f32x4 s3 = {}; s3 = MFMA16x16x32(ka, qf0, s3); sc[3] = MFMA16x16x32(kb2, qf1, s3);
        }
        kp0 += 64 * 1024; kp1 += 64 * 1024; kp2 += 64 * 1024; kp3 += 64 * 1024;

        // ---- bias + online softmax over 64 keys (state per q-row, 4 lane copies) ----
        float pmax = -1e30f;
        #pragma unroll
        for (int kt = 0; kt < 4; ++kt) {
            int nbase = qrow - (kv + kt * 16 + g * 4);
            #pragma unroll
            for (int e = 0; e < 4; ++e) {
                int n = nbase - e; n = n < 0 ? 0 : n;
                float val = sc[kt][e] + bts[n];
                sc[kt][e] = val;
                pmax = fmaxf(pmax, val);
            }
        }
        pmax = fmaxf(pmax, __shfl_xor(pmax, 16));
        pmax = fmaxf(pmax, __shfl_xor(pmax, 32));
        float mnew = fmaxf(mrun, pmax);
        float scale = exp2f(mrun - mnew);
        float rsum = 0.f;
        unsigned pk[8];
        #pragma unroll
        for (int kt = 0; kt < 4; ++kt) {
            float p0 = exp2f(sc[kt][0] - mnew);
            float p1 = exp2f(sc[kt][1] - mnew);
            float p2 = exp2f(sc[kt][2] - mnew);
            float p3 = exp2f(sc[kt][3] - mnew);
            rsum += (p0 + p1) + (p2 + p3);
            pk[kt * 2 + 0] = (unsigned)f2b(p0) | ((unsigned)f2b(p1) << 16);
            pk[kt * 2 + 1] = (unsigned)f2b(p2) | ((unsigned)f2b(p3) << 16);
        }
        rsum += __shfl_xor(rsum, 16);
        rsum += __shfl_xor(rsum, 32);
        lrun = lrun * scale + rsum;
        mrun = mnew;

        // ---- P to per-wave LDS (same-wave write->read, no barrier) ----
        #pragma unroll
        for (int kt = 0; kt < 4; ++kt) {
            uint2 u; u.x = pk[kt * 2]; u.y = pk[kt * 2 + 1];
            *reinterpret_cast<uint2*>(&Ps[w][r][kt * 16 + g * 4]) = u;
        }

        // ---- rescale O ----
        float s0 = __shfl(scale, g * 4 + 0);
        float s1 = __shfl(scale, g * 4 + 1);
        float s2 = __shfl(scale, g * 4 + 2);
        float s3 = __shfl(scale, g * 4 + 3);
        #pragma unroll
        for (int nt = 0; nt < 4; ++nt) {
            o[nt][0] *= s0; o[nt][1] *= s1; o[nt][2] *= s2; o[nt][3] *= s3;
        }

        // ---- PV: A = P[q][key-chunk], B = V^T fragments direct from global ----
        #pragma unroll
        for (int c = 0; c < 2; ++c) {
            bf16x8 pf = *reinterpret_cast<const bf16x8*>(&Ps[w][r][c * 32 + g * 8]);
            bf16x8 vf0 = *reinterpret_cast<const bf16x8*>(vp0 + c * 32);
            bf16x8 vf1 = *reinterpret_cast<const bf16x8*>(vp1 + c * 32);
            bf16x8 vf2 = *reinterpret_cast<const bf16x8*>(vp2 + c * 32);
            bf16x8 vf3 = *reinterpret_cast<const bf16x8*>(vp3 + c * 32);
            o[0] = MFMA16x16x32(pf, vf0, o[0]);
            o[1] = MFMA16x16x32(pf, vf1, o[1]);
            o[2] = MFMA16x16x32(pf, vf2, o[2]);
            o[3] = MFMA16x16x32(pf, vf3, o[3]);
        }
        vp0 += 64; vp1 += 64; vp2 += 64; vp3 += 64;
    }

    float l0 = __shfl(lrun, g * 4 + 0);
    float l1 = __shfl(lrun, g * 4 + 1);
    float l2 = __shfl(lrun, g * 4 + 2);
    float l3 = __shfl(lrun, g * 4 + 3);
    #pragma unroll
    for (int e = 0; e < 4; ++e) {
        int qr = qt * 64 + w * 16 + g * 4 + e;
        float li = (e == 0) ? l0 : (e == 1) ? l1 : (e == 2) ? l2 : l3;
        float inv = 1.0f / li;
        size_t ob = ((size_t)(b * 2048 + qr)) * 1024 + h * 64 + r;
        #pragma unroll
        for (int nt = 0; nt < 4; ++nt)
            out[ob + nt * 16] = o[nt][e] * inv;
    }
}

extern "C" void kernel_launch(void* const* d_in, const int* in_sizes, int n_in,
                              void* d_out, int out_size, void* d_ws, size_t ws_size,
                              hipStream_t stream) {
    const float* hidden = (const float*)d_in[0];
    const float* Wq = (const float*)d_in[1];
    const float* bq = (const float*)d_in[2];
    const float* Wk = (const float*)d_in[3];
    const float* bk = (const float*)d_in[4];
    const float* Wv = (const float*)d_in[5];
    const float* bv = (const float*)d_in[6];
    const float* rel_bias = (const float*)d_in[7];
    float* out = (float*)d_out;

    char* ws = (char*)d_ws;
    // ws layout: WT 6MB @0 | q 8MB @6M | k 8MB @14M | vt 16MB @22M | bt 128KB @38M  (38.1MB total)
    unsigned short* WT  = (unsigned short*)(ws);
    unsigned short* qws = (unsigned short*)(ws + (size_t)6 * 1024 * 1024);
    unsigned short* kws = (unsigned short*)(ws + (size_t)14 * 1024 * 1024);
    unsigned short* vtw = (unsigned short*)(ws + (size_t)22 * 1024 * 1024);
    float* bt           = (float*)(ws + (size_t)38 * 1024 * 1024);
    // bf16 copy of hidden parked in d_out (16MB); fully overwritten by attn afterwards.
    unsigned short* hA  = (unsigned short*)d_out;

    cvt_bf16_kernel<<<4096, 256, 0, stream>>>(hidden, hA, 4096 * 1024);
    transpose_cvt_kernel<<<dim3(32, 32, 3), dim3(32, 8), 0, stream>>>(Wq, Wk, Wv, WT);
    build_bt_kernel<<<8, 256, 0, stream>>>(rel_bias, bt);
    gemm_qkv_kernel<<<dim3(32, 8, 3), 256, 0, stream>>>(hA, WT, bq, bk, bv, qws, kws, vtw);
    attn_kernel<<<1024, 256, 0, stream>>>(qws, kws, vtw, bt, out);
}

// Round 3
// 240.877 us; speedup vs baseline: 1.5193x; 1.5193x over previous
//
#include <hip/hip_runtime.h>
#include <hip/hip_bf16.h>

typedef __attribute__((ext_vector_type(8))) short bf16x8;
typedef __attribute__((ext_vector_type(4))) float f32x4;

#define MFMA16x16x32(a, b, c) __builtin_amdgcn_mfma_f32_16x16x32_bf16(a, b, c, 0, 0, 0)
#define EXP2F(x) __builtin_amdgcn_exp2f(x)

#define LOG2E 1.44269504f
#define QSCALE (0.125f * 1.44269504f)

__device__ __forceinline__ unsigned short f2b(float x) {
    union { float f; unsigned int u; } v; v.f = x;
    unsigned int r = v.u + 0x7FFFu + ((v.u >> 16) & 1u);
    return (unsigned short)(r >> 16);
}

__device__ __forceinline__ void gload_lds16(const unsigned short* g, unsigned short* l) {
    __builtin_amdgcn_global_load_lds((const __attribute__((address_space(1))) void*)g,
                                     (__attribute__((address_space(3))) void*)l, 16, 0, 0);
}

// ---------------- fp32 -> bf16 convert (hidden states) ----------------
__global__ __launch_bounds__(256) void cvt_bf16_kernel(const float* __restrict__ in,
                                                       unsigned short* __restrict__ out, int n) {
    int i = (blockIdx.x * 256 + threadIdx.x) * 4;
    if (i >= n) return;
    float4 v = *reinterpret_cast<const float4*>(in + i);
    ushort4 o;
    o.x = f2b(v.x); o.y = f2b(v.y); o.z = f2b(v.z); o.w = f2b(v.w);
    *reinterpret_cast<ushort4*>(out + i) = o;
}

// ---------------- W [K][N] fp32 -> WT [N][K] bf16 (tiled transpose) ----------------
__global__ __launch_bounds__(256) void transpose_cvt_kernel(const float* __restrict__ Wq,
                                                            const float* __restrict__ Wk,
                                                            const float* __restrict__ Wv,
                                                            unsigned short* __restrict__ WTall) {
    int z = blockIdx.z;
    const float* in = (z == 0) ? Wq : (z == 1) ? Wk : Wv;
    unsigned short* outp = WTall + (size_t)z * 1024 * 1024;
    __shared__ float tile[32][33];
    int tx = threadIdx.x, ty = threadIdx.y;
    int x = blockIdx.x * 32 + tx;
    int y0 = blockIdx.y * 32;
    #pragma unroll
    for (int j = ty; j < 32; j += 8)
        tile[j][tx] = in[(size_t)(y0 + j) * 1024 + x];
    __syncthreads();
    int ox = y0 + tx;
    int oy0 = blockIdx.x * 32;
    #pragma unroll
    for (int j = ty; j < 32; j += 8)
        outp[(size_t)(oy0 + j) * 1024 + ox] = f2b(tile[tx][j]);
}

// ---------------- T5 bias LUT (pre-scaled by log2e): bt[h][n], n = max(q-k,0) ----------------
__global__ __launch_bounds__(256) void build_bt_kernel(const float* __restrict__ rel_bias,
                                                       float* __restrict__ bt) {
    int n = blockIdx.x * 256 + threadIdx.x;
    if (n >= 2048) return;
    int bucket;
    if (n < 16) {
        bucket = n;
    } else {
        float nf = (float)n;
        int v = 16 + (int)((logf(nf / 16.0f) / 0.69314718f) * 16.0f);
        bucket = v < 31 ? v : 31;
    }
    #pragma unroll
    for (int h = 0; h < 16; ++h)
        bt[(size_t)h * 2048 + n] = rel_bias[bucket * 16 + h] * LOG2E;
}

// ---------------- QKV projection GEMM (m97 structure: global_load_lds w=16) ----------------
__global__ __launch_bounds__(256) void gemm_qkv_kernel(const unsigned short* __restrict__ A,
                                                       const unsigned short* __restrict__ WTall,
                                                       const float* __restrict__ bq,
                                                       const float* __restrict__ bk,
                                                       const float* __restrict__ bv,
                                                       unsigned short* __restrict__ qws,
                                                       unsigned short* __restrict__ kws,
                                                       unsigned short* __restrict__ vtw) {
    const int K = 1024;
    int z = blockIdx.z;
    const unsigned short* Bm = WTall + (size_t)z * 1024 * 1024;
    const float* bias = (z == 0) ? bq : (z == 1) ? bk : bv;

    __shared__ unsigned short As[128 * 32];
    __shared__ unsigned short Bs[128 * 32];

    int t = threadIdx.x;
    int lane = t & 63, w = t >> 6;
    int wr = w >> 1, wc = w & 1;
    int g = lane >> 4, r = lane & 15;
    int m0 = blockIdx.x * 128, n0 = blockIdx.y * 128;

    int lrow = lane >> 2;
    int lcol = (lane & 3) * 8;
    const unsigned short* ga0 = A + (size_t)(m0 + w * 32 + lrow) * K + lcol;
    const unsigned short* ga1 = ga0 + 16 * K;
    const unsigned short* gb0 = Bm + (size_t)(n0 + w * 32 + lrow) * K + lcol;
    const unsigned short* gb1 = gb0 + 16 * K;
    unsigned short* lA0 = &As[(w * 32) * 32];
    unsigned short* lA1 = &As[(w * 32 + 16) * 32];
    unsigned short* lB0 = &Bs[(w * 32) * 32];
    unsigned short* lB1 = &Bs[(w * 32 + 16) * 32];

    f32x4 acc[4][4] = {};

    for (int kb = 0; kb < K; kb += 32) {
        gload_lds16(ga0 + kb, lA0);
        gload_lds16(ga1 + kb, lA1);
        gload_lds16(gb0 + kb, lB0);
        gload_lds16(gb1 + kb, lB1);
        __syncthreads();

        bf16x8 af[4], bfr[4];
        #pragma unroll
        for (int i = 0; i < 4; ++i)
            af[i] = *reinterpret_cast<const bf16x8*>(&As[(wr * 64 + i * 16 + r) * 32 + g * 8]);
        #pragma unroll
        for (int j = 0; j < 4; ++j)
            bfr[j] = *reinterpret_cast<const bf16x8*>(&Bs[(wc * 64 + j * 16 + r) * 32 + g * 8]);
        #pragma unroll
        for (int i = 0; i < 4; ++i) {
            #pragma unroll
            for (int j = 0; j < 4; ++j)
                acc[i][j] = MFMA16x16x32(af[i], bfr[j], acc[i][j]);
        }
        __syncthreads();
    }

    if (z < 2) {
        unsigned short* C = (z == 0) ? qws : kws;
        float sc = (z == 0) ? QSCALE : 1.0f;
        #pragma unroll
        for (int j = 0; j < 4; ++j) {
            int n = n0 + wc * 64 + j * 16 + r;
            float bj = bias[n];
            #pragma unroll
            for (int i = 0; i < 4; ++i) {
                int mbase = m0 + wr * 64 + i * 16 + g * 4;
                #pragma unroll
                for (int e = 0; e < 4; ++e)
                    C[(size_t)(mbase + e) * 1024 + n] = f2b((acc[i][j][e] + bj) * sc);
            }
        }
    } else {
        #pragma unroll
        for (int j = 0; j < 4; ++j) {
            int n = n0 + wc * 64 + j * 16 + r;
            int hh = n >> 6, d = n & 63;
            float bj = bias[n];
            #pragma unroll
            for (int i = 0; i < 4; ++i) {
                int mbase = m0 + wr * 64 + i * 16 + g * 4;
                int bb = mbase >> 11, s = mbase & 2047;
                ushort4 pk4;
                pk4.x = f2b(acc[i][j][0] + bj);
                pk4.y = f2b(acc[i][j][1] + bj);
                pk4.z = f2b(acc[i][j][2] + bj);
                pk4.w = f2b(acc[i][j][3] + bj);
                *reinterpret_cast<ushort4*>(vtw + ((size_t)((bb * 16 + hh) * 64 + d)) * 2048 + s) = pk4;
            }
        }
    }
}

// ---------------- Flash attention: LDS double-buffered K/V, KBLK=64, 1 barrier/iter ----------------
// Grid 1024 blocks; XCD swizzle groups all 32 q-tiles of a head on one XCD.
// 4 waves x 16 q-rows. Swapped QK^T; per-wave P round-trip via LDS; V pre-transposed (vt).
__global__ __launch_bounds__(256) void attn_kernel(const unsigned short* __restrict__ qg,
                                                   const unsigned short* __restrict__ kg,
                                                   const unsigned short* __restrict__ vt,
                                                   const float* __restrict__ bt,
                                                   float* __restrict__ out) {
    int p = blockIdx.x;
    int bh = (p & 7) | ((p >> 8) << 3);
    int qt = (p >> 3) & 31;
    int b = bh >> 4, h = bh & 15;
    int t = threadIdx.x;
    int lane = t & 63, w = t >> 6;
    int g = lane >> 4, r = lane & 15;

    __shared__ unsigned short Ks[2][64][72];   // [buf][key][d], +8 pad (144B rows: reads 2-way free)
    __shared__ unsigned short Vs[2][64][72];   // [buf][d][key]
    __shared__ unsigned short Ps[4][16][68];   // per-wave P [q=r][64 keys]
    __shared__ float bts[2048];

    for (int i = t; i < 2048; i += 256) bts[i] = bt[(size_t)h * 2048 + i];

    int qrow = qt * 64 + w * 16 + r;
    const unsigned short* qptr = qg + ((size_t)(b * 2048 + qrow)) * 1024 + h * 64;
    bf16x8 qf0 = *reinterpret_cast<const bf16x8*>(qptr + g * 8);
    bf16x8 qf1 = *reinterpret_cast<const bf16x8*>(qptr + 32 + g * 8);

    // staging map: thread t covers (srow, 8 elems) and (srow+32, 8 elems)
    int srow = t >> 3;                 // 0..31
    int sce = (t & 7) * 8;             // element offset in 64-wide window
    const size_t bh64 = (size_t)(b * 16 + h) * 64;
    const unsigned short* kgp = kg + (size_t)(b * 2048 + srow) * 1024 + h * 64 + sce;
    const unsigned short* vgp = vt + (bh64 + srow) * 2048 + sce;

    // prologue: stage tile 0 into buf 0
    {
        bf16x8 a0 = *reinterpret_cast<const bf16x8*>(kgp);
        bf16x8 a1 = *reinterpret_cast<const bf16x8*>(kgp + 32 * 1024);
        bf16x8 b0 = *reinterpret_cast<const bf16x8*>(vgp);
        bf16x8 b1 = *reinterpret_cast<const bf16x8*>(vgp + 32 * 2048);
        *reinterpret_cast<bf16x8*>(&Ks[0][srow][sce]) = a0;
        *reinterpret_cast<bf16x8*>(&Ks[0][srow + 32][sce]) = a1;
        *reinterpret_cast<bf16x8*>(&Vs[0][srow][sce]) = b0;
        *reinterpret_cast<bf16x8*>(&Vs[0][srow + 32][sce]) = b1;
    }
    kgp += 64 * 1024;   // advance to tile 1
    vgp += 64;
    __syncthreads();

    float mrun = -1e30f, lrun = 0.f;
    f32x4 o[4] = {};   // o[nt][e]: q = g*4+e, d = nt*16 + r
    int cur = 0;

    for (int kvi = 0; kvi < 32; ++kvi) {
        int kv = kvi * 64;
        bool hasnext = kvi < 31;
        bf16x8 nk0, nk1, nv0, nv1;
        if (hasnext) {
            nk0 = *reinterpret_cast<const bf16x8*>(kgp);
            nk1 = *reinterpret_cast<const bf16x8*>(kgp + 32 * 1024);
            nv0 = *reinterpret_cast<const bf16x8*>(vgp);
            nv1 = *reinterpret_cast<const bf16x8*>(vgp + 32 * 2048);
            kgp += 64 * 1024;
            vgp += 64;
        }

        // ---- QK^T (swapped): lane holds S[q=r][key = kv + kt*16 + g*4 + e] ----
        f32x4 sc[4];
        #pragma unroll
        for (int kt = 0; kt < 4; ++kt) {
            bf16x8 ka = *reinterpret_cast<const bf16x8*>(&Ks[cur][kt * 16 + r][g * 8]);
            bf16x8 kb2 = *reinterpret_cast<const bf16x8*>(&Ks[cur][kt * 16 + r][32 + g * 8]);
            f32x4 s = {};
            s = MFMA16x16x32(ka, qf0, s);
            sc[kt] = MFMA16x16x32(kb2, qf1, s);
        }

        // ---- bias + online softmax over 64 keys ----
        float pmax = -1e30f;
        #pragma unroll
        for (int kt = 0; kt < 4; ++kt) {
            int nbase = qrow - (kv + kt * 16 + g * 4);
            #pragma unroll
            for (int e = 0; e < 4; ++e) {
                int n = nbase - e; n = n < 0 ? 0 : n;
                float val = sc[kt][e] + bts[n];
                sc[kt][e] = val;
                pmax = fmaxf(pmax, val);
            }
        }
        pmax = fmaxf(pmax, __shfl_xor(pmax, 16));
        pmax = fmaxf(pmax, __shfl_xor(pmax, 32));
        float mnew = fmaxf(mrun, pmax);
        float scale = EXP2F(mrun - mnew);
        float rsum = 0.f;
        unsigned pk[8];
        #pragma unroll
        for (int kt = 0; kt < 4; ++kt) {
            float p0 = EXP2F(sc[kt][0] - mnew);
            float p1 = EXP2F(sc[kt][1] - mnew);
            float p2 = EXP2F(sc[kt][2] - mnew);
            float p3 = EXP2F(sc[kt][3] - mnew);
            rsum += (p0 + p1) + (p2 + p3);
            pk[kt * 2 + 0] = (unsigned)f2b(p0) | ((unsigned)f2b(p1) << 16);
            pk[kt * 2 + 1] = (unsigned)f2b(p2) | ((unsigned)f2b(p3) << 16);
        }
        rsum += __shfl_xor(rsum, 16);
        rsum += __shfl_xor(rsum, 32);
        lrun = lrun * scale + rsum;
        mrun = mnew;

        // ---- P to per-wave LDS (same-wave write->read) ----
        #pragma unroll
        for (int kt = 0; kt < 4; ++kt) {
            uint2 u; u.x = pk[kt * 2]; u.y = pk[kt * 2 + 1];
            *reinterpret_cast<uint2*>(&Ps[w][r][kt * 16 + g * 4]) = u;
        }

        // ---- rescale O ----
        float s0 = __shfl(scale, g * 4 + 0);
        float s1 = __shfl(scale, g * 4 + 1);
        float s2 = __shfl(scale, g * 4 + 2);
        float s3 = __shfl(scale, g * 4 + 3);
        #pragma unroll
        for (int nt = 0; nt < 4; ++nt) {
            o[nt][0] *= s0; o[nt][1] *= s1; o[nt][2] *= s2; o[nt][3] *= s3;
        }

        // ---- PV from LDS ----
        #pragma unroll
        for (int c = 0; c < 2; ++c) {
            bf16x8 pf = *reinterpret_cast<const bf16x8*>(&Ps[w][r][c * 32 + g * 8]);
            bf16x8 vf0 = *reinterpret_cast<const bf16x8*>(&Vs[cur][0 * 16 + r][c * 32 + g * 8]);
            bf16x8 vf1 = *reinterpret_cast<const bf16x8*>(&Vs[cur][1 * 16 + r][c * 32 + g * 8]);
            bf16x8 vf2 = *reinterpret_cast<const bf16x8*>(&Vs[cur][2 * 16 + r][c * 32 + g * 8]);
            bf16x8 vf3 = *reinterpret_cast<const bf16x8*>(&Vs[cur][3 * 16 + r][c * 32 + g * 8]);
            o[0] = MFMA16x16x32(pf, vf0, o[0]);
            o[1] = MFMA16x16x32(pf, vf1, o[1]);
            o[2] = MFMA16x16x32(pf, vf2, o[2]);
            o[3] = MFMA16x16x32(pf, vf3, o[3]);
        }

        // ---- write next tile into the other buffer, single barrier ----
        if (hasnext) {
            *reinterpret_cast<bf16x8*>(&Ks[cur ^ 1][srow][sce]) = nk0;
            *reinterpret_cast<bf16x8*>(&Ks[cur ^ 1][srow + 32][sce]) = nk1;
            *reinterpret_cast<bf16x8*>(&Vs[cur ^ 1][srow][sce]) = nv0;
            *reinterpret_cast<bf16x8*>(&Vs[cur ^ 1][srow + 32][sce]) = nv1;
        }
        __syncthreads();
        cur ^= 1;
    }

    float l0 = __shfl(lrun, g * 4 + 0);
    float l1 = __shfl(lrun, g * 4 + 1);
    float l2 = __shfl(lrun, g * 4 + 2);
    float l3 = __shfl(lrun, g * 4 + 3);
    #pragma unroll
    for (int e = 0; e < 4; ++e) {
        int qr = qt * 64 + w * 16 + g * 4 + e;
        float li = (e == 0) ? l0 : (e == 1) ? l1 : (e == 2) ? l2 : l3;
        float inv = 1.0f / li;
        size_t ob = ((size_t)(b * 2048 + qr)) * 1024 + h * 64 + r;
        #pragma unroll
        for (int nt = 0; nt < 4; ++nt)
            out[ob + nt * 16] = o[nt][e] * inv;
    }
}

extern "C" void kernel_launch(void* const* d_in, const int* in_sizes, int n_in,
                              void* d_out, int out_size, void* d_ws, size_t ws_size,
                              hipStream_t stream) {
    const float* hidden = (const float*)d_in[0];
    const float* Wq = (const float*)d_in[1];
    const float* bq = (const float*)d_in[2];
    const float* Wk = (const float*)d_in[3];
    const float* bk = (const float*)d_in[4];
    const float* Wv = (const float*)d_in[5];
    const float* bv = (const float*)d_in[6];
    const float* rel_bias = (const float*)d_in[7];
    float* out = (float*)d_out;

    char* ws = (char*)d_ws;
    // ws layout: WT 6MB @0 | q 8MB @6M | k 8MB @14M | vt 16MB @22M | bt 128KB @38M
    unsigned short* WT  = (unsigned short*)(ws);
    unsigned short* qws = (unsigned short*)(ws + (size_t)6 * 1024 * 1024);
    unsigned short* kws = (unsigned short*)(ws + (size_t)14 * 1024 * 1024);
    unsigned short* vtw = (unsigned short*)(ws + (size_t)22 * 1024 * 1024);
    float* bt           = (float*)(ws + (size_t)38 * 1024 * 1024);
    unsigned short* hA  = (unsigned short*)d_out;   // parked; overwritten by attn

    cvt_bf16_kernel<<<4096, 256, 0, stream>>>(hidden, hA, 4096 * 1024);
    transpose_cvt_kernel<<<dim3(32, 32, 3), dim3(32, 8), 0, stream>>>(Wq, Wk, Wv, WT);
    build_bt_kernel<<<8, 256, 0, stream>>>(rel_bias, bt);
    gemm_qkv_kernel<<<dim3(32, 8, 3), 256, 0, stream>>>(hA, WT, bq, bk, bv, qws, kws, vtw);
    attn_kernel<<<1024, 256, 0, stream>>>(qws, kws, vtw, bt, out);
}

// Round 4
// 235.337 us; speedup vs baseline: 1.5550x; 1.0235x over previous
//
#include <hip/hip_runtime.h>
#include <hip/hip_bf16.h>

typedef __attribute__((ext_vector_type(8))) short bf16x8;
typedef __attribute__((ext_vector_type(4))) float f32x4;

#define MFMA16x16x32(a, b, c) __builtin_amdgcn_mfma_f32_16x16x32_bf16(a, b, c, 0, 0, 0)
#define EXP2F(x) __builtin_amdgcn_exp2f(x)

#define LOG2E 1.44269504f
#define QSCALE (0.125f * 1.44269504f)

__device__ __forceinline__ unsigned short f2b(float x) {
    union { float f; unsigned int u; } v; v.f = x;
    unsigned int r = v.u + 0x7FFFu + ((v.u >> 16) & 1u);
    return (unsigned short)(r >> 16);
}

__device__ __forceinline__ unsigned pkbf2(float a, float b) {
    float2 f; f.x = a; f.y = b;
    __hip_bfloat162 h = __float22bfloat162_rn(f);
    union { __hip_bfloat162 h2; unsigned u; } cv; cv.h2 = h;
    return cv.u;
}

__device__ __forceinline__ void gload_lds16(const unsigned short* g, unsigned short* l) {
    __builtin_amdgcn_global_load_lds((const __attribute__((address_space(1))) void*)g,
                                     (__attribute__((address_space(3))) void*)l, 16, 0, 0);
}

__device__ __forceinline__ f32x4 fmax4(f32x4 a, f32x4 b) {
    f32x4 r;
    r[0] = fmaxf(a[0], b[0]); r[1] = fmaxf(a[1], b[1]);
    r[2] = fmaxf(a[2], b[2]); r[3] = fmaxf(a[3], b[3]);
    return r;
}

// ---------------- fp32 -> bf16 convert (hidden states) ----------------
__global__ __launch_bounds__(256) void cvt_bf16_kernel(const float* __restrict__ in,
                                                       unsigned short* __restrict__ out, int n) {
    int i = (blockIdx.x * 256 + threadIdx.x) * 4;
    if (i >= n) return;
    float4 v = *reinterpret_cast<const float4*>(in + i);
    ushort4 o;
    o.x = f2b(v.x); o.y = f2b(v.y); o.z = f2b(v.z); o.w = f2b(v.w);
    *reinterpret_cast<ushort4*>(out + i) = o;
}

// ---------------- W [K][N] fp32 -> WT [N][K] bf16 (tiled transpose) ----------------
__global__ __launch_bounds__(256) void transpose_cvt_kernel(const float* __restrict__ Wq,
                                                            const float* __restrict__ Wk,
                                                            const float* __restrict__ Wv,
                                                            unsigned short* __restrict__ WTall) {
    int z = blockIdx.z;
    const float* in = (z == 0) ? Wq : (z == 1) ? Wk : Wv;
    unsigned short* outp = WTall + (size_t)z * 1024 * 1024;
    __shared__ float tile[32][33];
    int tx = threadIdx.x, ty = threadIdx.y;
    int x = blockIdx.x * 32 + tx;
    int y0 = blockIdx.y * 32;
    #pragma unroll
    for (int j = ty; j < 32; j += 8)
        tile[j][tx] = in[(size_t)(y0 + j) * 1024 + x];
    __syncthreads();
    int ox = y0 + tx;
    int oy0 = blockIdx.x * 32;
    #pragma unroll
    for (int j = ty; j < 32; j += 8)
        outp[(size_t)(oy0 + j) * 1024 + ox] = f2b(tile[tx][j]);
}

// ---------------- T5 bias LUT (pre-scaled by log2e): bt[h][n], n = max(q-k,0) ----------------
__global__ __launch_bounds__(256) void build_bt_kernel(const float* __restrict__ rel_bias,
                                                       float* __restrict__ bt) {
    int n = blockIdx.x * 256 + threadIdx.x;
    if (n >= 2048) return;
    int bucket;
    if (n < 16) {
        bucket = n;
    } else {
        float nf = (float)n;
        int v = 16 + (int)((logf(nf / 16.0f) / 0.69314718f) * 16.0f);
        bucket = v < 31 ? v : 31;
    }
    #pragma unroll
    for (int h = 0; h < 16; ++h)
        bt[(size_t)h * 2048 + n] = rel_bias[bucket * 16 + h] * LOG2E;
}

// ---------------- QKV projection GEMM (m97 structure: global_load_lds w=16) ----------------
__global__ __launch_bounds__(256) void gemm_qkv_kernel(const unsigned short* __restrict__ A,
                                                       const unsigned short* __restrict__ WTall,
                                                       const float* __restrict__ bq,
                                                       const float* __restrict__ bk,
                                                       const float* __restrict__ bv,
                                                       unsigned short* __restrict__ qws,
                                                       unsigned short* __restrict__ kws,
                                                       unsigned short* __restrict__ vtw) {
    const int K = 1024;
    int z = blockIdx.z;
    const unsigned short* Bm = WTall + (size_t)z * 1024 * 1024;
    const float* bias = (z == 0) ? bq : (z == 1) ? bk : bv;

    __shared__ unsigned short As[128 * 32];
    __shared__ unsigned short Bs[128 * 32];

    int t = threadIdx.x;
    int lane = t & 63, w = t >> 6;
    int wr = w >> 1, wc = w & 1;
    int g = lane >> 4, r = lane & 15;
    int m0 = blockIdx.x * 128, n0 = blockIdx.y * 128;

    int lrow = lane >> 2;
    int lcol = (lane & 3) * 8;
    const unsigned short* ga0 = A + (size_t)(m0 + w * 32 + lrow) * K + lcol;
    const unsigned short* ga1 = ga0 + 16 * K;
    const unsigned short* gb0 = Bm + (size_t)(n0 + w * 32 + lrow) * K + lcol;
    const unsigned short* gb1 = gb0 + 16 * K;
    unsigned short* lA0 = &As[(w * 32) * 32];
    unsigned short* lA1 = &As[(w * 32 + 16) * 32];
    unsigned short* lB0 = &Bs[(w * 32) * 32];
    unsigned short* lB1 = &Bs[(w * 32 + 16) * 32];

    f32x4 acc[4][4] = {};

    for (int kb = 0; kb < K; kb += 32) {
        gload_lds16(ga0 + kb, lA0);
        gload_lds16(ga1 + kb, lA1);
        gload_lds16(gb0 + kb, lB0);
        gload_lds16(gb1 + kb, lB1);
        __syncthreads();

        bf16x8 af[4], bfr[4];
        #pragma unroll
        for (int i = 0; i < 4; ++i)
            af[i] = *reinterpret_cast<const bf16x8*>(&As[(wr * 64 + i * 16 + r) * 32 + g * 8]);
        #pragma unroll
        for (int j = 0; j < 4; ++j)
            bfr[j] = *reinterpret_cast<const bf16x8*>(&Bs[(wc * 64 + j * 16 + r) * 32 + g * 8]);
        #pragma unroll
        for (int i = 0; i < 4; ++i) {
            #pragma unroll
            for (int j = 0; j < 4; ++j)
                acc[i][j] = MFMA16x16x32(af[i], bfr[j], acc[i][j]);
        }
        __syncthreads();
    }

    if (z < 2) {
        unsigned short* C = (z == 0) ? qws : kws;
        float sc = (z == 0) ? QSCALE : 1.0f;
        #pragma unroll
        for (int j = 0; j < 4; ++j) {
            int n = n0 + wc * 64 + j * 16 + r;
            float bj = bias[n];
            #pragma unroll
            for (int i = 0; i < 4; ++i) {
                int mbase = m0 + wr * 64 + i * 16 + g * 4;
                #pragma unroll
                for (int e = 0; e < 4; ++e)
                    C[(size_t)(mbase + e) * 1024 + n] = f2b((acc[i][j][e] + bj) * sc);
            }
        }
    } else {
        #pragma unroll
        for (int j = 0; j < 4; ++j) {
            int n = n0 + wc * 64 + j * 16 + r;
            int hh = n >> 6, d = n & 63;
            float bj = bias[n];
            #pragma unroll
            for (int i = 0; i < 4; ++i) {
                int mbase = m0 + wr * 64 + i * 16 + g * 4;
                int bb = mbase >> 11, s = mbase & 2047;
                ushort4 pk4;
                pk4.x = f2b(acc[i][j][0] + bj);
                pk4.y = f2b(acc[i][j][1] + bj);
                pk4.z = f2b(acc[i][j][2] + bj);
                pk4.w = f2b(acc[i][j][3] + bj);
                *reinterpret_cast<ushort4*>(vtw + ((size_t)((bb * 16 + hh) * 64 + d)) * 2048 + s) = pk4;
            }
        }
    }
}

// ---------------- Flash attention v4 ----------------
// 4 waves x 16 q-rows, KVBLK=64, double-buffered LDS (stride-70 rows: ~2-way banks).
// Tile-constant bias for non-diagonal tiles; defer-max; l via ones-MFMA; setprio on MFMA.
__global__ __launch_bounds__(256, 3) void attn_kernel(const unsigned short* __restrict__ qg,
                                                      const unsigned short* __restrict__ kg,
                                                      const unsigned short* __restrict__ vt,
                                                      const float* __restrict__ bt,
                                                      float* __restrict__ out) {
    int p = blockIdx.x;
    int bh = (p & 7) | ((p >> 8) << 3);
    int qt = (p >> 3) & 31;
    int b = bh >> 4, h = bh & 15;
    int t = threadIdx.x;
    int lane = t & 63, w = t >> 6;
    int g = lane >> 4, r = lane & 15;

    __shared__ unsigned short Ks[2][64][70];   // stride 140B -> ~2-way banks
    __shared__ unsigned short Vs[2][64][70];
    __shared__ unsigned short Ps[4][16][70];
    __shared__ float bts128[128];              // diagonal tiles only need n in [0,127]

    if (t < 128) bts128[t] = bt[(size_t)h * 2048 + t];

    int qrow = qt * 64 + w * 16 + r;
    const unsigned short* qptr = qg + ((size_t)(b * 2048 + qrow)) * 1024 + h * 64;
    bf16x8 qf0 = *reinterpret_cast<const bf16x8*>(qptr + g * 8);
    bf16x8 qf1 = *reinterpret_cast<const bf16x8*>(qptr + 32 + g * 8);

    bf16x8 vones;
    #pragma unroll
    for (int j = 0; j < 8; ++j) vones[j] = (short)0x3F80;   // bf16 1.0

    int srow = t >> 3;
    int sce = (t & 7) * 8;
    const size_t bh64 = (size_t)(b * 16 + h) * 64;
    const unsigned short* kgp = kg + (size_t)(b * 2048 + srow) * 1024 + h * 64 + sce;
    const unsigned short* vgp = vt + (bh64 + srow) * 2048 + sce;

    {
        bf16x8 a0 = *reinterpret_cast<const bf16x8*>(kgp);
        bf16x8 a1 = *reinterpret_cast<const bf16x8*>(kgp + 32 * 1024);
        bf16x8 b0 = *reinterpret_cast<const bf16x8*>(vgp);
        bf16x8 b1 = *reinterpret_cast<const bf16x8*>(vgp + 32 * 2048);
        *reinterpret_cast<bf16x8*>(&Ks[0][srow][sce]) = a0;
        *reinterpret_cast<bf16x8*>(&Ks[0][srow + 32][sce]) = a1;
        *reinterpret_cast<bf16x8*>(&Vs[0][srow][sce]) = b0;
        *reinterpret_cast<bf16x8*>(&Vs[0][srow + 32][sce]) = b1;
    }
    kgp += 64 * 1024;
    vgp += 64;
    __syncthreads();

    float b0c = bts128[0];     // bias constant for future tiles (n=0)
    float b31c = bts128[31];   // bias constant for far-past tiles (n>=31)

    float mrun = -1e30f;
    f32x4 o[4] = {};           // o[nt][e]: q = g*4+e, d = nt*16 + r
    f32x4 o4 = {};             // softmax denominator via ones-MFMA (same q mapping)

    #pragma unroll 2
    for (int kvi = 0; kvi < 32; ++kvi) {
        int kv = kvi * 64;
        int cur = kvi & 1;
        bool hasnext = kvi < 31;
        bf16x8 nk0, nk1, nv0, nv1;
        if (hasnext) {
            nk0 = *reinterpret_cast<const bf16x8*>(kgp);
            nk1 = *reinterpret_cast<const bf16x8*>(kgp + 32 * 1024);
            nv0 = *reinterpret_cast<const bf16x8*>(vgp);
            nv1 = *reinterpret_cast<const bf16x8*>(vgp + 32 * 2048);
            kgp += 64 * 1024;
            vgp += 64;
        }

        // ---- QK^T (swapped): lane holds S[q=r][key = kv + kt*16 + g*4 + e] ----
        f32x4 sc[4];
        __builtin_amdgcn_s_setprio(1);
        #pragma unroll
        for (int kt = 0; kt < 4; ++kt) {
            bf16x8 ka = *reinterpret_cast<const bf16x8*>(&Ks[cur][kt * 16 + r][g * 8]);
            bf16x8 kb2 = *reinterpret_cast<const bf16x8*>(&Ks[cur][kt * 16 + r][32 + g * 8]);
            f32x4 s = {};
            s = MFMA16x16x32(ka, qf0, s);
            sc[kt] = MFMA16x16x32(kb2, qf1, s);
        }
        __builtin_amdgcn_s_setprio(0);

        // ---- bias ----
        int dqt = qt - kvi;
        bool slow = (dqt == 0) || (dqt == 1);     // wave-uniform
        float cb = slow ? 0.f : (dqt >= 2 ? b31c : b0c);
        if (slow) {
            #pragma unroll
            for (int kt = 0; kt < 4; ++kt) {
                int nbase = qrow - (kv + kt * 16 + g * 4);
                #pragma unroll
                for (int e = 0; e < 4; ++e) {
                    int n = nbase - e; n = n < 0 ? 0 : n;
                    sc[kt][e] += bts128[n];
                }
            }
        }

        // ---- online softmax with defer-max ----
        f32x4 mx = fmax4(fmax4(sc[0], sc[1]), fmax4(sc[2], sc[3]));
        float pmax = fmaxf(fmaxf(mx[0], mx[1]), fmaxf(mx[2], mx[3]));
        pmax = fmaxf(pmax, __shfl_xor(pmax, 16));
        pmax = fmaxf(pmax, __shfl_xor(pmax, 32));
        float pb = pmax + cb;
        if (!__all(pb - mrun <= 8.0f)) {
            float mnew = fmaxf(mrun, pb);
            float scale = EXP2F(mrun - mnew);
            float s0 = __shfl(scale, g * 4 + 0);
            float s1 = __shfl(scale, g * 4 + 1);
            float s2 = __shfl(scale, g * 4 + 2);
            float s3 = __shfl(scale, g * 4 + 3);
            #pragma unroll
            for (int nt = 0; nt < 4; ++nt) {
                o[nt][0] *= s0; o[nt][1] *= s1; o[nt][2] *= s2; o[nt][3] *= s3;
            }
            o4[0] *= s0; o4[1] *= s1; o4[2] *= s2; o4[3] *= s3;
            mrun = mnew;
        }
        float moff = mrun - cb;

        #pragma unroll
        for (int kt = 0; kt < 4; ++kt) {
            float p0 = EXP2F(sc[kt][0] - moff);
            float p1 = EXP2F(sc[kt][1] - moff);
            float p2 = EXP2F(sc[kt][2] - moff);
            float p3 = EXP2F(sc[kt][3] - moff);
            uint2 u;
            u.x = pkbf2(p0, p1);
            u.y = pkbf2(p2, p3);
            *reinterpret_cast<uint2*>(&Ps[w][r][kt * 16 + g * 4]) = u;
        }

        // ---- PV + denominator (ones column) ----
        __builtin_amdgcn_s_setprio(1);
        #pragma unroll
        for (int c = 0; c < 2; ++c) {
            bf16x8 pf = *reinterpret_cast<const bf16x8*>(&Ps[w][r][c * 32 + g * 8]);
            bf16x8 vf0 = *reinterpret_cast<const bf16x8*>(&Vs[cur][0 * 16 + r][c * 32 + g * 8]);
            bf16x8 vf1 = *reinterpret_cast<const bf16x8*>(&Vs[cur][1 * 16 + r][c * 32 + g * 8]);
            bf16x8 vf2 = *reinterpret_cast<const bf16x8*>(&Vs[cur][2 * 16 + r][c * 32 + g * 8]);
            bf16x8 vf3 = *reinterpret_cast<const bf16x8*>(&Vs[cur][3 * 16 + r][c * 32 + g * 8]);
            o[0] = MFMA16x16x32(pf, vf0, o[0]);
            o[1] = MFMA16x16x32(pf, vf1, o[1]);
            o[2] = MFMA16x16x32(pf, vf2, o[2]);
            o[3] = MFMA16x16x32(pf, vf3, o[3]);
            o4 = MFMA16x16x32(pf, vones, o4);
        }
        __builtin_amdgcn_s_setprio(0);

        // ---- stage next tile, single barrier ----
        if (hasnext) {
            *reinterpret_cast<bf16x8*>(&Ks[cur ^ 1][srow][sce]) = nk0;
            *reinterpret_cast<bf16x8*>(&Ks[cur ^ 1][srow + 32][sce]) = nk1;
            *reinterpret_cast<bf16x8*>(&Vs[cur ^ 1][srow][sce]) = nv0;
            *reinterpret_cast<bf16x8*>(&Vs[cur ^ 1][srow + 32][sce]) = nv1;
        }
        __syncthreads();
    }

    #pragma unroll
    for (int e = 0; e < 4; ++e) {
        int qr = qt * 64 + w * 16 + g * 4 + e;
        float inv = 1.0f / o4[e];
        size_t ob = ((size_t)(b * 2048 + qr)) * 1024 + h * 64 + r;
        #pragma unroll
        for (int nt = 0; nt < 4; ++nt)
            out[ob + nt * 16] = o[nt][e] * inv;
    }
}

extern "C" void kernel_launch(void* const* d_in, const int* in_sizes, int n_in,
                              void* d_out, int out_size, void* d_ws, size_t ws_size,
                              hipStream_t stream) {
    const float* hidden = (const float*)d_in[0];
    const float* Wq = (const float*)d_in[1];
    const float* bq = (const float*)d_in[2];
    const float* Wk = (const float*)d_in[3];
    const float* bk = (const float*)d_in[4];
    const float* Wv = (const float*)d_in[5];
    const float* bv = (const float*)d_in[6];
    const float* rel_bias = (const float*)d_in[7];
    float* out = (float*)d_out;

    char* ws = (char*)d_ws;
    // ws layout: WT 6MB @0 | q 8MB @6M | k 8MB @14M | vt 16MB @22M | bt 128KB @38M
    unsigned short* WT  = (unsigned short*)(ws);
    unsigned short* qws = (unsigned short*)(ws + (size_t)6 * 1024 * 1024);
    unsigned short* kws = (unsigned short*)(ws + (size_t)14 * 1024 * 1024);
    unsigned short* vtw = (unsigned short*)(ws + (size_t)22 * 1024 * 1024);
    float* bt           = (float*)(ws + (size_t)38 * 1024 * 1024);
    unsigned short* hA  = (unsigned short*)d_out;   // parked; overwritten by attn

    cvt_bf16_kernel<<<4096, 256, 0, stream>>>(hidden, hA, 4096 * 1024);
    transpose_cvt_kernel<<<dim3(32, 32, 3), dim3(32, 8), 0, stream>>>(Wq, Wk, Wv, WT);
    build_bt_kernel<<<8, 256, 0, stream>>>(rel_bias, bt);
    gemm_qkv_kernel<<<dim3(32, 8, 3), 256, 0, stream>>>(hA, WT, bq, bk, bv, qws, kws, vtw);
    attn_kernel<<<1024, 256, 0, stream>>>(qws, kws, vtw, bt, out);
}

// Round 6
// 216.437 us; speedup vs baseline: 1.6908x; 1.0873x over previous
//
#include <hip/hip_runtime.h>
#include <hip/hip_bf16.h>

typedef __attribute__((ext_vector_type(8))) short bf16x8;
typedef __attribute__((ext_vector_type(4))) float f32x4;

#define MFMA16x16x32(a, b, c) __builtin_amdgcn_mfma_f32_16x16x32_bf16(a, b, c, 0, 0, 0)
#define EXP2F(x) __builtin_amdgcn_exp2f(x)

#define LOG2E 1.44269504f
#define QSCALE (0.125f * 1.44269504f)

__device__ __forceinline__ unsigned short f2b(float x) {
    union { float f; unsigned int u; } v; v.f = x;
    unsigned int r = v.u + 0x7FFFu + ((v.u >> 16) & 1u);
    return (unsigned short)(r >> 16);
}

__device__ __forceinline__ unsigned pkbf2(float a, float b) {
    float2 f; f.x = a; f.y = b;
    __hip_bfloat162 h = __float22bfloat162_rn(f);
    union { __hip_bfloat162 h2; unsigned u; } cv; cv.h2 = h;
    return cv.u;
}

__device__ __forceinline__ void gload_lds16(const unsigned short* g, unsigned short* l) {
    __builtin_amdgcn_global_load_lds((const __attribute__((address_space(1))) void*)g,
                                     (__attribute__((address_space(3))) void*)l, 16, 0, 0);
}

__device__ __forceinline__ f32x4 fmax4(f32x4 a, f32x4 b) {
    f32x4 r;
    r[0] = fmaxf(a[0], b[0]); r[1] = fmaxf(a[1], b[1]);
    r[2] = fmaxf(a[2], b[2]); r[3] = fmaxf(a[3], b[3]);
    return r;
}

// ---------------- fp32 -> bf16 convert (hidden states) ----------------
__global__ __launch_bounds__(256) void cvt_bf16_kernel(const float* __restrict__ in,
                                                       unsigned short* __restrict__ out, int n) {
    int i = (blockIdx.x * 256 + threadIdx.x) * 4;
    if (i >= n) return;
    float4 v = *reinterpret_cast<const float4*>(in + i);
    ushort4 o;
    o.x = f2b(v.x); o.y = f2b(v.y); o.z = f2b(v.z); o.w = f2b(v.w);
    *reinterpret_cast<ushort4*>(out + i) = o;
}

// ---------------- W [K][N] fp32 -> WT [N][K] bf16 (tiled transpose) ----------------
__global__ __launch_bounds__(256) void transpose_cvt_kernel(const float* __restrict__ Wq,
                                                            const float* __restrict__ Wk,
                                                            const float* __restrict__ Wv,
                                                            unsigned short* __restrict__ WTall) {
    int z = blockIdx.z;
    const float* in = (z == 0) ? Wq : (z == 1) ? Wk : Wv;
    unsigned short* outp = WTall + (size_t)z * 1024 * 1024;
    __shared__ float tile[32][33];
    int tx = threadIdx.x, ty = threadIdx.y;
    int x = blockIdx.x * 32 + tx;
    int y0 = blockIdx.y * 32;
    #pragma unroll
    for (int j = ty; j < 32; j += 8)
        tile[j][tx] = in[(size_t)(y0 + j) * 1024 + x];
    __syncthreads();
    int ox = y0 + tx;
    int oy0 = blockIdx.x * 32;
    #pragma unroll
    for (int j = ty; j < 32; j += 8)
        outp[(size_t)(oy0 + j) * 1024 + ox] = f2b(tile[tx][j]);
}

// ---------------- T5 bias LUT (pre-scaled by log2e): bt[h][n], n = max(q-k,0) ----------------
__global__ __launch_bounds__(256) void build_bt_kernel(const float* __restrict__ rel_bias,
                                                       float* __restrict__ bt) {
    int n = blockIdx.x * 256 + threadIdx.x;
    if (n >= 2048) return;
    int bucket;
    if (n < 16) {
        bucket = n;
    } else {
        float nf = (float)n;
        int v = 16 + (int)((logf(nf / 16.0f) / 0.69314718f) * 16.0f);
        bucket = v < 31 ? v : 31;
    }
    #pragma unroll
    for (int h = 0; h < 16; ++h)
        bt[(size_t)h * 2048 + n] = rel_bias[bucket * 16 + h] * LOG2E;
}

// ---------------- QKV projection GEMM (m97 structure: global_load_lds w=16) ----------------
__global__ __launch_bounds__(256) void gemm_qkv_kernel(const unsigned short* __restrict__ A,
                                                       const unsigned short* __restrict__ WTall,
                                                       const float* __restrict__ bq,
                                                       const float* __restrict__ bk,
                                                       const float* __restrict__ bv,
                                                       unsigned short* __restrict__ qws,
                                                       unsigned short* __restrict__ kws,
                                                       unsigned short* __restrict__ vtw) {
    const int K = 1024;
    int z = blockIdx.z;
    const unsigned short* Bm = WTall + (size_t)z * 1024 * 1024;
    const float* bias = (z == 0) ? bq : (z == 1) ? bk : bv;

    __shared__ unsigned short As[128 * 32];
    __shared__ unsigned short Bs[128 * 32];

    int t = threadIdx.x;
    int lane = t & 63, w = t >> 6;
    int wr = w >> 1, wc = w & 1;
    int g = lane >> 4, r = lane & 15;
    int m0 = blockIdx.x * 128, n0 = blockIdx.y * 128;

    int lrow = lane >> 2;
    int lcol = (lane & 3) * 8;
    const unsigned short* ga0 = A + (size_t)(m0 + w * 32 + lrow) * K + lcol;
    const unsigned short* ga1 = ga0 + 16 * K;
    const unsigned short* gb0 = Bm + (size_t)(n0 + w * 32 + lrow) * K + lcol;
    const unsigned short* gb1 = gb0 + 16 * K;
    unsigned short* lA0 = &As[(w * 32) * 32];
    unsigned short* lA1 = &As[(w * 32 + 16) * 32];
    unsigned short* lB0 = &Bs[(w * 32) * 32];
    unsigned short* lB1 = &Bs[(w * 32 + 16) * 32];

    f32x4 acc[4][4] = {};

    for (int kb = 0; kb < K; kb += 32) {
        gload_lds16(ga0 + kb, lA0);
        gload_lds16(ga1 + kb, lA1);
        gload_lds16(gb0 + kb, lB0);
        gload_lds16(gb1 + kb, lB1);
        __syncthreads();

        bf16x8 af[4], bfr[4];
        #pragma unroll
        for (int i = 0; i < 4; ++i)
            af[i] = *reinterpret_cast<const bf16x8*>(&As[(wr * 64 + i * 16 + r) * 32 + g * 8]);
        #pragma unroll
        for (int j = 0; j < 4; ++j)
            bfr[j] = *reinterpret_cast<const bf16x8*>(&Bs[(wc * 64 + j * 16 + r) * 32 + g * 8]);
        #pragma unroll
        for (int i = 0; i < 4; ++i) {
            #pragma unroll
            for (int j = 0; j < 4; ++j)
                acc[i][j] = MFMA16x16x32(af[i], bfr[j], acc[i][j]);
        }
        __syncthreads();
    }

    if (z < 2) {
        unsigned short* C = (z == 0) ? qws : kws;
        float sc = (z == 0) ? QSCALE : 1.0f;
        #pragma unroll
        for (int j = 0; j < 4; ++j) {
            int n = n0 + wc * 64 + j * 16 + r;
            float bj = bias[n];
            #pragma unroll
            for (int i = 0; i < 4; ++i) {
                int mbase = m0 + wr * 64 + i * 16 + g * 4;
                #pragma unroll
                for (int e = 0; e < 4; ++e)
                    C[(size_t)(mbase + e) * 1024 + n] = f2b((acc[i][j][e] + bj) * sc);
            }
        }
    } else {
        #pragma unroll
        for (int j = 0; j < 4; ++j) {
            int n = n0 + wc * 64 + j * 16 + r;
            int hh = n >> 6, d = n & 63;
            float bj = bias[n];
            #pragma unroll
            for (int i = 0; i < 4; ++i) {
                int mbase = m0 + wr * 64 + i * 16 + g * 4;
                int bb = mbase >> 11, s = mbase & 2047;
                ushort4 pk4;
                pk4.x = f2b(acc[i][j][0] + bj);
                pk4.y = f2b(acc[i][j][1] + bj);
                pk4.z = f2b(acc[i][j][2] + bj);
                pk4.w = f2b(acc[i][j][3] + bj);
                *reinterpret_cast<ushort4*>(vtw + ((size_t)((bb * 16 + hh) * 64 + d)) * 2048 + s) = pk4;
            }
        }
    }
}

// ---------------- Flash attention v5: zero-shuffle PV ----------------
// 4 waves x 16 q-rows, KVBLK=64, double-buffered LDS. V columns stored PERMUTED per
// 32-chunk (position p'=g*8+j holds key (j>=4)*16+g*4+(j&3)) so the softmax output
// registers ARE the PV A-fragment -- P never touches LDS. l via ones-MFMA (perm-invariant).
__global__ __launch_bounds__(256, 4) void attn_kernel(const unsigned short* __restrict__ qg,
                                                      const unsigned short* __restrict__ kg,
                                                      const unsigned short* __restrict__ vt,
                                                      const float* __restrict__ bt,
                                                      float* __restrict__ out) {
    int p = blockIdx.x;
    int bh = (p & 7) | ((p >> 8) << 3);
    int qt = (p >> 3) & 31;
    int b = bh >> 4, h = bh & 15;
    int t = threadIdx.x;
    int lane = t & 63, w = t >> 6;
    int g = lane >> 4, r = lane & 15;

    __shared__ unsigned short Ks[2][64][70];   // natural [key][d]
    __shared__ unsigned short Vs[2][64][70];   // [d][key-permuted]
    __shared__ float bts128[128];

    if (t < 128) bts128[t] = bt[(size_t)h * 2048 + t];

    int qrow = qt * 64 + w * 16 + r;
    const unsigned short* qptr = qg + ((size_t)(b * 2048 + qrow)) * 1024 + h * 64;
    bf16x8 qf0 = *reinterpret_cast<const bf16x8*>(qptr + g * 8);
    bf16x8 qf1 = *reinterpret_cast<const bf16x8*>(qptr + 32 + g * 8);

    bf16x8 vones;
    #pragma unroll
    for (int j = 0; j < 8; ++j) vones[j] = (short)0x3F80;   // bf16 1.0

    int srow = t >> 3;                 // 0..31
    int s = t & 7;
    int sce = s * 8;
    // permuted V column base: c = s>>2, sigma = s&3
    int vcol = (s >> 2) * 32 + (s & 1) * 16 + ((s >> 1) & 1) * 4;
    const size_t bh64 = (size_t)(b * 16 + h) * 64;
    const unsigned short* kgp = kg + (size_t)(b * 2048 + srow) * 1024 + h * 64 + sce;
    const unsigned short* vgp = vt + (bh64 + srow) * 2048 + sce;

    {
        bf16x8 a0 = *reinterpret_cast<const bf16x8*>(kgp);
        bf16x8 a1 = *reinterpret_cast<const bf16x8*>(kgp + 32 * 1024);
        bf16x8 b0 = *reinterpret_cast<const bf16x8*>(vgp);
        bf16x8 b1 = *reinterpret_cast<const bf16x8*>(vgp + 32 * 2048);
        *reinterpret_cast<bf16x8*>(&Ks[0][srow][sce]) = a0;
        *reinterpret_cast<bf16x8*>(&Ks[0][srow + 32][sce]) = a1;
        ushort4 lo, hi;
        lo.x = (unsigned short)b0[0]; lo.y = (unsigned short)b0[1];
        lo.z = (unsigned short)b0[2]; lo.w = (unsigned short)b0[3];
        hi.x = (unsigned short)b0[4]; hi.y = (unsigned short)b0[5];
        hi.z = (unsigned short)b0[6]; hi.w = (unsigned short)b0[7];
        *reinterpret_cast<ushort4*>(&Vs[0][srow][vcol]) = lo;
        *reinterpret_cast<ushort4*>(&Vs[0][srow][vcol + 8]) = hi;
        lo.x = (unsigned short)b1[0]; lo.y = (unsigned short)b1[1];
        lo.z = (unsigned short)b1[2]; lo.w = (unsigned short)b1[3];
        hi.x = (unsigned short)b1[4]; hi.y = (unsigned short)b1[5];
        hi.z = (unsigned short)b1[6]; hi.w = (unsigned short)b1[7];
        *reinterpret_cast<ushort4*>(&Vs[0][srow + 32][vcol]) = lo;
        *reinterpret_cast<ushort4*>(&Vs[0][srow + 32][vcol + 8]) = hi;
    }
    kgp += 64 * 1024;
    vgp += 64;
    __syncthreads();

    float b0c = bts128[0];     // bias constant for future tiles (n=0)
    float b31c = bts128[31];   // bias constant for far-past tiles (n>=31)

    float mrun = -1e30f;
    f32x4 o[4] = {};           // o[nt][e]: q = g*4+e, d = nt*16 + r
    f32x4 o4 = {};             // softmax denominator

    #pragma unroll 2
    for (int kvi = 0; kvi < 32; ++kvi) {
        int kv = kvi * 64;
        int cur = kvi & 1;
        bool hasnext = kvi < 31;
        bf16x8 nk0, nk1, nv0, nv1;
        if (hasnext) {
            nk0 = *reinterpret_cast<const bf16x8*>(kgp);
            nk1 = *reinterpret_cast<const bf16x8*>(kgp + 32 * 1024);
            nv0 = *reinterpret_cast<const bf16x8*>(vgp);
            nv1 = *reinterpret_cast<const bf16x8*>(vgp + 32 * 2048);
            kgp += 64 * 1024;
            vgp += 64;
        }

        // ---- QK^T (swapped): lane holds S[q=r][key = kv + kt*16 + g*4 + e] ----
        f32x4 sc[4];
        __builtin_amdgcn_s_setprio(1);
        #pragma unroll
        for (int kt = 0; kt < 4; ++kt) {
            bf16x8 ka = *reinterpret_cast<const bf16x8*>(&Ks[cur][kt * 16 + r][g * 8]);
            bf16x8 kb2 = *reinterpret_cast<const bf16x8*>(&Ks[cur][kt * 16 + r][32 + g * 8]);
            f32x4 sacc = {};
            sacc = MFMA16x16x32(ka, qf0, sacc);
            sc[kt] = MFMA16x16x32(kb2, qf1, sacc);
        }
        __builtin_amdgcn_s_setprio(0);

        // ---- bias ----
        int dqt = qt - kvi;
        bool slow = (dqt == 0) || (dqt == 1);     // wave-uniform
        float cb = slow ? 0.f : (dqt >= 2 ? b31c : b0c);
        if (slow) {
            #pragma unroll
            for (int kt = 0; kt < 4; ++kt) {
                int nbase = qrow - (kv + kt * 16 + g * 4);
                #pragma unroll
                for (int e = 0; e < 4; ++e) {
                    int n = nbase - e; n = n < 0 ? 0 : n;
                    sc[kt][e] += bts128[n];
                }
            }
        }

        // ---- online softmax with defer-max ----
        f32x4 mx = fmax4(fmax4(sc[0], sc[1]), fmax4(sc[2], sc[3]));
        float pmax = fmaxf(fmaxf(mx[0], mx[1]), fmaxf(mx[2], mx[3]));
        pmax = fmaxf(pmax, __shfl_xor(pmax, 16));
        pmax = fmaxf(pmax, __shfl_xor(pmax, 32));
        float pb = pmax + cb;
        if (!__all(pb - mrun <= 8.0f)) {
            float mnew = fmaxf(mrun, pb);
            float scale = EXP2F(mrun - mnew);
            float s0 = __shfl(scale, g * 4 + 0);
            float s1 = __shfl(scale, g * 4 + 1);
            float s2 = __shfl(scale, g * 4 + 2);
            float s3 = __shfl(scale, g * 4 + 3);
            #pragma unroll
            for (int nt = 0; nt < 4; ++nt) {
                o[nt][0] *= s0; o[nt][1] *= s1; o[nt][2] *= s2; o[nt][3] *= s3;
            }
            o4[0] *= s0; o4[1] *= s1; o4[2] *= s2; o4[3] *= s3;
            mrun = mnew;
        }
        float moff = mrun - cb;

        // ---- exp2 into packed registers: u[kt*2+half] ARE the PV A-fragments ----
        union { unsigned u[8]; bf16x8 v2[2]; } pku;
        #pragma unroll
        for (int kt = 0; kt < 4; ++kt) {
            float p0 = EXP2F(sc[kt][0] - moff);
            float p1 = EXP2F(sc[kt][1] - moff);
            float p2 = EXP2F(sc[kt][2] - moff);
            float p3 = EXP2F(sc[kt][3] - moff);
            pku.u[kt * 2 + 0] = pkbf2(p0, p1);
            pku.u[kt * 2 + 1] = pkbf2(p2, p3);
        }

        // ---- PV + denominator: A-fragment direct from registers (V columns permuted) ----
        __builtin_amdgcn_s_setprio(1);
        #pragma unroll
        for (int c = 0; c < 2; ++c) {
            bf16x8 pf = pku.v2[c];
            bf16x8 vf0 = *reinterpret_cast<const bf16x8*>(&Vs[cur][0 * 16 + r][c * 32 + g * 8]);
            bf16x8 vf1 = *reinterpret_cast<const bf16x8*>(&Vs[cur][1 * 16 + r][c * 32 + g * 8]);
            bf16x8 vf2 = *reinterpret_cast<const bf16x8*>(&Vs[cur][2 * 16 + r][c * 32 + g * 8]);
            bf16x8 vf3 = *reinterpret_cast<const bf16x8*>(&Vs[cur][3 * 16 + r][c * 32 + g * 8]);
            o[0] = MFMA16x16x32(pf, vf0, o[0]);
            o[1] = MFMA16x16x32(pf, vf1, o[1]);
            o[2] = MFMA16x16x32(pf, vf2, o[2]);
            o[3] = MFMA16x16x32(pf, vf3, o[3]);
            o4 = MFMA16x16x32(pf, vones, o4);
        }
        __builtin_amdgcn_s_setprio(0);

        // ---- stage next tile (K natural, V permuted), single barrier ----
        if (hasnext) {
            *reinterpret_cast<bf16x8*>(&Ks[cur ^ 1][srow][sce]) = nk0;
            *reinterpret_cast<bf16x8*>(&Ks[cur ^ 1][srow + 32][sce]) = nk1;
            ushort4 lo, hi;
            lo.x = (unsigned short)nv0[0]; lo.y = (unsigned short)nv0[1];
            lo.z = (unsigned short)nv0[2]; lo.w = (unsigned short)nv0[3];
            hi.x = (unsigned short)nv0[4]; hi.y = (unsigned short)nv0[5];
            hi.z = (unsigned short)nv0[6]; hi.w = (unsigned short)nv0[7];
            *reinterpret_cast<ushort4*>(&Vs[cur ^ 1][srow][vcol]) = lo;
            *reinterpret_cast<ushort4*>(&Vs[cur ^ 1][srow][vcol + 8]) = hi;
            lo.x = (unsigned short)nv1[0]; lo.y = (unsigned short)nv1[1];
            lo.z = (unsigned short)nv1[2]; lo.w = (unsigned short)nv1[3];
            hi.x = (unsigned short)nv1[4]; hi.y = (unsigned short)nv1[5];
            hi.z = (unsigned short)nv1[6]; hi.w = (unsigned short)nv1[7];
            *reinterpret_cast<ushort4*>(&Vs[cur ^ 1][srow + 32][vcol]) = lo;
            *reinterpret_cast<ushort4*>(&Vs[cur ^ 1][srow + 32][vcol + 8]) = hi;
        }
        __syncthreads();
    }

    #pragma unroll
    for (int e = 0; e < 4; ++e) {
        int qr = qt * 64 + w * 16 + g * 4 + e;
        float inv = 1.0f / o4[e];
        size_t ob = ((size_t)(b * 2048 + qr)) * 1024 + h * 64 + r;
        #pragma unroll
        for (int nt = 0; nt < 4; ++nt)
            out[ob + nt * 16] = o[nt][e] * inv;
    }
}

extern "C" void kernel_launch(void* const* d_in, const int* in_sizes, int n_in,
                              void* d_out, int out_size, void* d_ws, size_t ws_size,
                              hipStream_t stream) {
    const float* hidden = (const float*)d_in[0];
    const float* Wq = (const float*)d_in[1];
    const float* bq = (const float*)d_in[2];
    const float* Wk = (const float*)d_in[3];
    const float* bk = (const float*)d_in[4];
    const float* Wv = (const float*)d_in[5];
    const float* bv = (const float*)d_in[6];
    const float* rel_bias = (const float*)d_in[7];
    float* out = (float*)d_out;

    char* ws = (char*)d_ws;
    // ws layout: WT 6MB @0 | q 8MB @6M | k 8MB @14M | vt 16MB @22M | bt 128KB @38M
    unsigned short* WT  = (unsigned short*)(ws);
    unsigned short* qws = (unsigned short*)(ws + (size_t)6 * 1024 * 1024);
    unsigned short* kws = (unsigned short*)(ws + (size_t)14 * 1024 * 1024);
    unsigned short* vtw = (unsigned short*)(ws + (size_t)22 * 1024 * 1024);
    float* bt           = (float*)(ws + (size_t)38 * 1024 * 1024);
    unsigned short* hA  = (unsigned short*)d_out;   // parked; overwritten by attn

    cvt_bf16_kernel<<<4096, 256, 0, stream>>>(hidden, hA, 4096 * 1024);
    transpose_cvt_kernel<<<dim3(32, 32, 3), dim3(32, 8), 0, stream>>>(Wq, Wk, Wv, WT);
    build_bt_kernel<<<8, 256, 0, stream>>>(rel_bias, bt);
    gemm_qkv_kernel<<<dim3(32, 8, 3), 256, 0, stream>>>(hA, WT, bq, bk, bv, qws, kws, vtw);
    attn_kernel<<<1024, 256, 0, stream>>>(qws, kws, vtw, bt, out);
}

// Round 7
// 195.340 us; speedup vs baseline: 1.8734x; 1.1080x over previous
//
#include <hip/hip_runtime.h>
#include <hip/hip_bf16.h>

typedef __attribute__((ext_vector_type(8))) short bf16x8;
typedef __attribute__((ext_vector_type(4))) float f32x4;

#define MFMA16x16x32(a, b, c) __builtin_amdgcn_mfma_f32_16x16x32_bf16(a, b, c, 0, 0, 0)
#define EXP2F(x) __builtin_amdgcn_exp2f(x)

#define LOG2E 1.44269504f
#define QSCALE (0.125f * 1.44269504f)

__device__ __forceinline__ unsigned short f2b(float x) {
    union { float f; unsigned int u; } v; v.f = x;
    unsigned int r = v.u + 0x7FFFu + ((v.u >> 16) & 1u);
    return (unsigned short)(r >> 16);
}

__device__ __forceinline__ unsigned pkbf2(float a, float b) {
    float2 f; f.x = a; f.y = b;
    __hip_bfloat162 h = __float22bfloat162_rn(f);
    union { __hip_bfloat162 h2; unsigned u; } cv; cv.h2 = h;
    return cv.u;
}

__device__ __forceinline__ void gload_lds16(const unsigned short* g, unsigned short* l) {
    __builtin_amdgcn_global_load_lds((const __attribute__((address_space(1))) void*)g,
                                     (__attribute__((address_space(3))) void*)l, 16, 0, 0);
}

__device__ __forceinline__ f32x4 fmax4(f32x4 a, f32x4 b) {
    f32x4 r;
    r[0] = fmaxf(a[0], b[0]); r[1] = fmaxf(a[1], b[1]);
    r[2] = fmaxf(a[2], b[2]); r[3] = fmaxf(a[3], b[3]);
    return r;
}

// ---------------- fp32 -> bf16 convert (hidden states) ----------------
__global__ __launch_bounds__(256) void cvt_bf16_kernel(const float* __restrict__ in,
                                                       unsigned short* __restrict__ out, int n) {
    int i = (blockIdx.x * 256 + threadIdx.x) * 4;
    if (i >= n) return;
    float4 v = *reinterpret_cast<const float4*>(in + i);
    ushort4 o;
    o.x = f2b(v.x); o.y = f2b(v.y); o.z = f2b(v.z); o.w = f2b(v.w);
    *reinterpret_cast<ushort4*>(out + i) = o;
}

// ---------------- W [K][N] fp32 -> WT [N][K] bf16 (tiled transpose) ----------------
__global__ __launch_bounds__(256) void transpose_cvt_kernel(const float* __restrict__ Wq,
                                                            const float* __restrict__ Wk,
                                                            const float* __restrict__ Wv,
                                                            unsigned short* __restrict__ WTall) {
    int z = blockIdx.z;
    const float* in = (z == 0) ? Wq : (z == 1) ? Wk : Wv;
    unsigned short* outp = WTall + (size_t)z * 1024 * 1024;
    __shared__ float tile[32][33];
    int tx = threadIdx.x, ty = threadIdx.y;
    int x = blockIdx.x * 32 + tx;
    int y0 = blockIdx.y * 32;
    #pragma unroll
    for (int j = ty; j < 32; j += 8)
        tile[j][tx] = in[(size_t)(y0 + j) * 1024 + x];
    __syncthreads();
    int ox = y0 + tx;
    int oy0 = blockIdx.x * 32;
    #pragma unroll
    for (int j = ty; j < 32; j += 8)
        outp[(size_t)(oy0 + j) * 1024 + ox] = f2b(tile[tx][j]);
}

// ---------------- T5 bias LUT (pre-scaled by log2e): bt[h][n], n = max(q-k,0) ----------------
__global__ __launch_bounds__(256) void build_bt_kernel(const float* __restrict__ rel_bias,
                                                       float* __restrict__ bt) {
    int n = blockIdx.x * 256 + threadIdx.x;
    if (n >= 2048) return;
    int bucket;
    if (n < 16) {
        bucket = n;
    } else {
        float nf = (float)n;
        int v = 16 + (int)((logf(nf / 16.0f) / 0.69314718f) * 16.0f);
        bucket = v < 31 ? v : 31;
    }
    #pragma unroll
    for (int h = 0; h < 16; ++h)
        bt[(size_t)h * 2048 + n] = rel_bias[bucket * 16 + h] * LOG2E;
}

// ---------------- QKV projection GEMM (m97 structure + XCD chunk swizzle) ----------------
// vt output is PRE-PERMUTED per 32-key chunk so the attn kernel's zero-shuffle PV can
// stage V with plain b128 copies: within chunk, key kk lives at position
// p = ((kk>>2)&3)*8 + ((kk>>4)&1)*4 + (kk&3).
__global__ __launch_bounds__(256) void gemm_qkv_kernel(const unsigned short* __restrict__ A,
                                                       const unsigned short* __restrict__ WTall,
                                                       const float* __restrict__ bq,
                                                       const float* __restrict__ bk,
                                                       const float* __restrict__ bv,
                                                       unsigned short* __restrict__ qws,
                                                       unsigned short* __restrict__ kws,
                                                       unsigned short* __restrict__ vtw) {
    const int K = 1024;
    // 1-D grid 768, XCD chunk swizzle: 96 consecutive logical blocks per XCD
    int p = blockIdx.x;
    int lid = (p & 7) * 96 + (p >> 3);
    int bx = lid & 31;
    int rem = lid >> 5;
    int by = rem & 7;
    int z = rem >> 3;

    const unsigned short* Bm = WTall + (size_t)z * 1024 * 1024;
    const float* bias = (z == 0) ? bq : (z == 1) ? bk : bv;

    __shared__ unsigned short As[128 * 32];
    __shared__ unsigned short Bs[128 * 32];

    int t = threadIdx.x;
    int lane = t & 63, w = t >> 6;
    int wr = w >> 1, wc = w & 1;
    int g = lane >> 4, r = lane & 15;
    int m0 = bx * 128, n0 = by * 128;

    int lrow = lane >> 2;
    int lcol = (lane & 3) * 8;
    const unsigned short* ga0 = A + (size_t)(m0 + w * 32 + lrow) * K + lcol;
    const unsigned short* ga1 = ga0 + 16 * K;
    const unsigned short* gb0 = Bm + (size_t)(n0 + w * 32 + lrow) * K + lcol;
    const unsigned short* gb1 = gb0 + 16 * K;
    unsigned short* lA0 = &As[(w * 32) * 32];
    unsigned short* lA1 = &As[(w * 32 + 16) * 32];
    unsigned short* lB0 = &Bs[(w * 32) * 32];
    unsigned short* lB1 = &Bs[(w * 32 + 16) * 32];

    f32x4 acc[4][4] = {};

    for (int kb = 0; kb < K; kb += 32) {
        gload_lds16(ga0 + kb, lA0);
        gload_lds16(ga1 + kb, lA1);
        gload_lds16(gb0 + kb, lB0);
        gload_lds16(gb1 + kb, lB1);
        __syncthreads();

        bf16x8 af[4], bfr[4];
        #pragma unroll
        for (int i = 0; i < 4; ++i)
            af[i] = *reinterpret_cast<const bf16x8*>(&As[(wr * 64 + i * 16 + r) * 32 + g * 8]);
        #pragma unroll
        for (int j = 0; j < 4; ++j)
            bfr[j] = *reinterpret_cast<const bf16x8*>(&Bs[(wc * 64 + j * 16 + r) * 32 + g * 8]);
        #pragma unroll
        for (int i = 0; i < 4; ++i) {
            #pragma unroll
            for (int j = 0; j < 4; ++j)
                acc[i][j] = MFMA16x16x32(af[i], bfr[j], acc[i][j]);
        }
        __syncthreads();
    }

    if (z < 2) {
        unsigned short* C = (z == 0) ? qws : kws;
        float sc = (z == 0) ? QSCALE : 1.0f;
        #pragma unroll
        for (int j = 0; j < 4; ++j) {
            int n = n0 + wc * 64 + j * 16 + r;
            float bj = bias[n];
            #pragma unroll
            for (int i = 0; i < 4; ++i) {
                int mbase = m0 + wr * 64 + i * 16 + g * 4;
                #pragma unroll
                for (int e = 0; e < 4; ++e)
                    C[(size_t)(mbase + e) * 1024 + n] = f2b((acc[i][j][e] + bj) * sc);
            }
        }
    } else {
        #pragma unroll
        for (int j = 0; j < 4; ++j) {
            int n = n0 + wc * 64 + j * 16 + r;
            int hh = n >> 6, d = n & 63;
            float bj = bias[n];
            #pragma unroll
            for (int i = 0; i < 4; ++i) {
                int mbase = m0 + wr * 64 + i * 16 + g * 4;   // s base (mult of 4)
                int bb = mbase >> 11;
                int kk5 = mbase & 31;
                int pbase = ((kk5 >> 2) & 3) * 8 + ((kk5 >> 4) & 1) * 4;
                int sp = ((mbase & 2047) & ~31) | pbase;     // permuted s within 2048
                ushort4 pk4;
                pk4.x = f2b(acc[i][j][0] + bj);
                pk4.y = f2b(acc[i][j][1] + bj);
                pk4.z = f2b(acc[i][j][2] + bj);
                pk4.w = f2b(acc[i][j][3] + bj);
                *reinterpret_cast<ushort4*>(vtw + ((size_t)((bb * 16 + hh) * 64 + d)) * 2048 + sp) = pk4;
            }
        }
    }
}

// ---------------- Flash attention v6: 32 q-rows per wave, zero-shuffle PV ----------------
// QBLK=128 (4 waves x 32 rows as two 16-row groups sharing K/V fragment reads).
// Grid 512, XCD swizzle (64 logical blocks per XCD = 4 heads' K/V in L2).
// LDS stride 72 (144B rows): 16B-aligned b128, ~minimal bank cycles.
// V arrives pre-permuted from the GEMM epilogue -> plain b128 staging.
__global__ __launch_bounds__(256, 2) void attn_kernel(const unsigned short* __restrict__ qg,
                                                      const unsigned short* __restrict__ kg,
                                                      const unsigned short* __restrict__ vt,
                                                      const float* __restrict__ bt,
                                                      float* __restrict__ out) {
    int p = blockIdx.x;
    int lid = (p & 7) * 64 + (p >> 3);
    int bh = lid >> 4, qt = lid & 15;
    int b = bh >> 4, h = bh & 15;
    int t = threadIdx.x;
    int lane = t & 63, w = t >> 6;
    int g = lane >> 4, r = lane & 15;

    __shared__ unsigned short Ks[2][64][72];
    __shared__ unsigned short Vs[2][64][72];
    __shared__ float bts[256];

    bts[t] = bt[(size_t)h * 2048 + t];   // 256 threads -> full table

    int q0 = qt * 128 + w * 32 + r;      // group-0 q row for this lane
    int q1 = q0 + 16;                    // group-1
    const unsigned short* qp0 = qg + ((size_t)(b * 2048 + q0)) * 1024 + h * 64;
    const unsigned short* qp1 = qg + ((size_t)(b * 2048 + q1)) * 1024 + h * 64;
    bf16x8 qa0 = *reinterpret_cast<const bf16x8*>(qp0 + g * 8);
    bf16x8 qb0 = *reinterpret_cast<const bf16x8*>(qp0 + 32 + g * 8);
    bf16x8 qa1 = *reinterpret_cast<const bf16x8*>(qp1 + g * 8);
    bf16x8 qb1 = *reinterpret_cast<const bf16x8*>(qp1 + 32 + g * 8);

    bf16x8 vones;
    #pragma unroll
    for (int j = 0; j < 8; ++j) vones[j] = (short)0x3F80;

    int srow = t >> 3;                   // 0..31
    int sce = (t & 7) * 8;
    const unsigned short* kgp = kg + (size_t)(b * 2048 + srow) * 1024 + h * 64 + sce;
    const unsigned short* vgp = vt + ((size_t)(b * 16 + h) * 64 + srow) * 2048 + sce;

    {
        bf16x8 a0 = *reinterpret_cast<const bf16x8*>(kgp);
        bf16x8 a1 = *reinterpret_cast<const bf16x8*>(kgp + 32 * 1024);
        bf16x8 b0 = *reinterpret_cast<const bf16x8*>(vgp);
        bf16x8 b1 = *reinterpret_cast<const bf16x8*>(vgp + 32 * 2048);
        *reinterpret_cast<bf16x8*>(&Ks[0][srow][sce]) = a0;
        *reinterpret_cast<bf16x8*>(&Ks[0][srow + 32][sce]) = a1;
        *reinterpret_cast<bf16x8*>(&Vs[0][srow][sce]) = b0;
        *reinterpret_cast<bf16x8*>(&Vs[0][srow + 32][sce]) = b1;
    }
    kgp += 64 * 1024;
    vgp += 64;
    __syncthreads();

    float b0c = bts[0];      // future tiles: n = 0
    float b31c = bts[31];    // far-past tiles: n >= 31 -> bucket 31

    float mr0 = -1e30f, mr1 = -1e30f;
    f32x4 o0[4] = {}, o1[4] = {};
    f32x4 d0 = {}, d1 = {};             // denominators via ones-MFMA

    #pragma unroll 2
    for (int kvi = 0; kvi < 32; ++kvi) {
        int kv = kvi * 64;
        int cur = kvi & 1;
        bool hasnext = kvi < 31;
        bf16x8 nk0, nk1, nv0, nv1;
        if (hasnext) {
            nk0 = *reinterpret_cast<const bf16x8*>(kgp);
            nk1 = *reinterpret_cast<const bf16x8*>(kgp + 32 * 1024);
            nv0 = *reinterpret_cast<const bf16x8*>(vgp);
            nv1 = *reinterpret_cast<const bf16x8*>(vgp + 32 * 2048);
            kgp += 64 * 1024;
            vgp += 64;
        }

        // ---- QK^T (swapped), both groups share K fragments ----
        f32x4 sc0[4], sc1[4];
        __builtin_amdgcn_s_setprio(1);
        #pragma unroll
        for (int kt = 0; kt < 4; ++kt) {
            bf16x8 ka = *reinterpret_cast<const bf16x8*>(&Ks[cur][kt * 16 + r][g * 8]);
            bf16x8 kb2 = *reinterpret_cast<const bf16x8*>(&Ks[cur][kt * 16 + r][32 + g * 8]);
            f32x4 s0 = {}; s0 = MFMA16x16x32(ka, qa0, s0); sc0[kt] = MFMA16x16x32(kb2, qb0, s0);
            f32x4 s1 = {}; s1 = MFMA16x16x32(ka, qa1, s1); sc1[kt] = MFMA16x16x32(kb2, qb1, s1);
        }
        __builtin_amdgcn_s_setprio(0);

        // ---- bias ----
        int dd = 2 * qt - kvi;                       // tile-diagonal distance
        bool slow = (dd >= -1) && (dd <= 1);
        float cb = slow ? 0.f : (dd >= 2 ? b31c : b0c);
        if (slow) {
            #pragma unroll
            for (int kt = 0; kt < 4; ++kt) {
                int nb0 = q0 - (kv + kt * 16 + g * 4);
                int nb1 = nb0 + 16;
                #pragma unroll
                for (int e = 0; e < 4; ++e) {
                    int n0i = nb0 - e; n0i = n0i < 0 ? 0 : n0i;
                    int n1i = nb1 - e; n1i = n1i < 0 ? 0 : n1i;
                    sc0[kt][e] += bts[n0i];
                    sc1[kt][e] += bts[n1i];
                }
            }
        }

        // ---- online softmax per group (defer-max) ----
        union { unsigned u[8]; bf16x8 v2[2]; } pk0, pk1;
        {
            f32x4 mx = fmax4(fmax4(sc0[0], sc0[1]), fmax4(sc0[2], sc0[3]));
            float pmax = fmaxf(fmaxf(mx[0], mx[1]), fmaxf(mx[2], mx[3]));
            pmax = fmaxf(pmax, __shfl_xor(pmax, 16));
            pmax = fmaxf(pmax, __shfl_xor(pmax, 32));
            float pb = pmax + cb;
            if (!__all(pb - mr0 <= 8.0f)) {
                float mnew = fmaxf(mr0, pb);
                float scale = EXP2F(mr0 - mnew);
                float s0 = __shfl(scale, g * 4 + 0);
                float s1 = __shfl(scale, g * 4 + 1);
                float s2 = __shfl(scale, g * 4 + 2);
                float s3 = __shfl(scale, g * 4 + 3);
                #pragma unroll
                for (int nt = 0; nt < 4; ++nt) {
                    o0[nt][0] *= s0; o0[nt][1] *= s1; o0[nt][2] *= s2; o0[nt][3] *= s3;
                }
                d0[0] *= s0; d0[1] *= s1; d0[2] *= s2; d0[3] *= s3;
                mr0 = mnew;
            }
            float moff = mr0 - cb;
            #pragma unroll
            for (int kt = 0; kt < 4; ++kt) {
                float p0 = EXP2F(sc0[kt][0] - moff);
                float p1 = EXP2F(sc0[kt][1] - moff);
                float p2 = EXP2F(sc0[kt][2] - moff);
                float p3 = EXP2F(sc0[kt][3] - moff);
                pk0.u[kt * 2 + 0] = pkbf2(p0, p1);
                pk0.u[kt * 2 + 1] = pkbf2(p2, p3);
            }
        }
        {
            f32x4 mx = fmax4(fmax4(sc1[0], sc1[1]), fmax4(sc1[2], sc1[3]));
            float pmax = fmaxf(fmaxf(mx[0], mx[1]), fmaxf(mx[2], mx[3]));
            pmax = fmaxf(pmax, __shfl_xor(pmax, 16));
            pmax = fmaxf(pmax, __shfl_xor(pmax, 32));
            float pb = pmax + cb;
            if (!__all(pb - mr1 <= 8.0f)) {
                float mnew = fmaxf(mr1, pb);
                float scale = EXP2F(mr1 - mnew);
                float s0 = __shfl(scale, g * 4 + 0);
                float s1 = __shfl(scale, g * 4 + 1);
                float s2 = __shfl(scale, g * 4 + 2);
                float s3 = __shfl(scale, g * 4 + 3);
                #pragma unroll
                for (int nt = 0; nt < 4; ++nt) {
                    o1[nt][0] *= s0; o1[nt][1] *= s1; o1[nt][2] *= s2; o1[nt][3] *= s3;
                }
                d1[0] *= s0; d1[1] *= s1; d1[2] *= s2; d1[3] *= s3;
                mr1 = mnew;
            }
            float moff = mr1 - cb;
            #pragma unroll
            for (int kt = 0; kt < 4; ++kt) {
                float p0 = EXP2F(sc1[kt][0] - moff);
                float p1 = EXP2F(sc1[kt][1] - moff);
                float p2 = EXP2F(sc1[kt][2] - moff);
                float p3 = EXP2F(sc1[kt][3] - moff);
                pk1.u[kt * 2 + 0] = pkbf2(p0, p1);
                pk1.u[kt * 2 + 1] = pkbf2(p2, p3);
            }
        }

        // ---- PV + denominators: V fragments shared by both groups ----
        __builtin_amdgcn_s_setprio(1);
        #pragma unroll
        for (int c = 0; c < 2; ++c) {
            bf16x8 pf0 = pk0.v2[c];
            bf16x8 pf1 = pk1.v2[c];
            bf16x8 vf0 = *reinterpret_cast<const bf16x8*>(&Vs[cur][0 * 16 + r][c * 32 + g * 8]);
            bf16x8 vf1 = *reinterpret_cast<const bf16x8*>(&Vs[cur][1 * 16 + r][c * 32 + g * 8]);
            bf16x8 vf2 = *reinterpret_cast<const bf16x8*>(&Vs[cur][2 * 16 + r][c * 32 + g * 8]);
            bf16x8 vf3 = *reinterpret_cast<const bf16x8*>(&Vs[cur][3 * 16 + r][c * 32 + g * 8]);
            o0[0] = MFMA16x16x32(pf0, vf0, o0[0]);
            o1[0] = MFMA16x16x32(pf1, vf0, o1[0]);
            o0[1] = MFMA16x16x32(pf0, vf1, o0[1]);
            o1[1] = MFMA16x16x32(pf1, vf1, o1[1]);
            o0[2] = MFMA16x16x32(pf0, vf2, o0[2]);
            o1[2] = MFMA16x16x32(pf1, vf2, o1[2]);
            o0[3] = MFMA16x16x32(pf0, vf3, o0[3]);
            o1[3] = MFMA16x16x32(pf1, vf3, o1[3]);
            d0 = MFMA16x16x32(pf0, vones, d0);
            d1 = MFMA16x16x32(pf1, vones, d1);
        }
        __builtin_amdgcn_s_setprio(0);

        // ---- stage next tile, single barrier ----
        if (hasnext) {
            *reinterpret_cast<bf16x8*>(&Ks[cur ^ 1][srow][sce]) = nk0;
            *reinterpret_cast<bf16x8*>(&Ks[cur ^ 1][srow + 32][sce]) = nk1;
            *reinterpret_cast<bf16x8*>(&Vs[cur ^ 1][srow][sce]) = nv0;
            *reinterpret_cast<bf16x8*>(&Vs[cur ^ 1][srow + 32][sce]) = nv1;
        }
        __syncthreads();
    }

    #pragma unroll
    for (int e = 0; e < 4; ++e) {
        int qr0 = qt * 128 + w * 32 + g * 4 + e;
        float inv0 = 1.0f / d0[e];
        size_t ob0 = ((size_t)(b * 2048 + qr0)) * 1024 + h * 64 + r;
        float inv1 = 1.0f / d1[e];
        size_t ob1 = ob0 + (size_t)16 * 1024;
        #pragma unroll
        for (int nt = 0; nt < 4; ++nt) {
            out[ob0 + nt * 16] = o0[nt][e] * inv0;
            out[ob1 + nt * 16] = o1[nt][e] * inv1;
        }
    }
}

extern "C" void kernel_launch(void* const* d_in, const int* in_sizes, int n_in,
                              void* d_out, int out_size, void* d_ws, size_t ws_size,
                              hipStream_t stream) {
    const float* hidden = (const float*)d_in[0];
    const float* Wq = (const float*)d_in[1];
    const float* bq = (const float*)d_in[2];
    const float* Wk = (const float*)d_in[3];
    const float* bk = (const float*)d_in[4];
    const float* Wv = (const float*)d_in[5];
    const float* bv = (const float*)d_in[6];
    const float* rel_bias = (const float*)d_in[7];
    float* out = (float*)d_out;

    char* ws = (char*)d_ws;
    // ws layout: WT 6MB @0 | q 8MB @6M | k 8MB @14M | vt 16MB @22M | bt 128KB @38M
    unsigned short* WT  = (unsigned short*)(ws);
    unsigned short* qws = (unsigned short*)(ws + (size_t)6 * 1024 * 1024);
    unsigned short* kws = (unsigned short*)(ws + (size_t)14 * 1024 * 1024);
    unsigned short* vtw = (unsigned short*)(ws + (size_t)22 * 1024 * 1024);
    float* bt           = (float*)(ws + (size_t)38 * 1024 * 1024);
    unsigned short* hA  = (unsigned short*)d_out;   // parked; overwritten by attn

    cvt_bf16_kernel<<<4096, 256, 0, stream>>>(hidden, hA, 4096 * 1024);
    transpose_cvt_kernel<<<dim3(32, 32, 3), dim3(32, 8), 0, stream>>>(Wq, Wk, Wv, WT);
    build_bt_kernel<<<8, 256, 0, stream>>>(rel_bias, bt);
    gemm_qkv_kernel<<<768, 256, 0, stream>>>(hA, WT, bq, bk, bv, qws, kws, vtw);
    attn_kernel<<<512, 256, 0, stream>>>(qws, kws, vtw, bt, out);
}

// Round 8
// 193.209 us; speedup vs baseline: 1.8941x; 1.0110x over previous
//
#include <hip/hip_runtime.h>
#include <hip/hip_bf16.h>

typedef __attribute__((ext_vector_type(8))) short bf16x8;
typedef __attribute__((ext_vector_type(4))) float f32x4;

#define MFMA16x16x32(a, b, c) __builtin_amdgcn_mfma_f32_16x16x32_bf16(a, b, c, 0, 0, 0)
#define EXP2F(x) __builtin_amdgcn_exp2f(x)

#define LOG2E 1.44269504f
#define QSCALE (0.125f * 1.44269504f)

__device__ __forceinline__ unsigned short f2b(float x) {
    union { float f; unsigned int u; } v; v.f = x;
    unsigned int r = v.u + 0x7FFFu + ((v.u >> 16) & 1u);
    return (unsigned short)(r >> 16);
}

__device__ __forceinline__ unsigned pkbf2(float a, float b) {
    float2 f; f.x = a; f.y = b;
    __hip_bfloat162 h = __float22bfloat162_rn(f);
    union { __hip_bfloat162 h2; unsigned u; } cv; cv.h2 = h;
    return cv.u;
}

__device__ __forceinline__ void gload_lds16(const unsigned short* g, unsigned short* l) {
    __builtin_amdgcn_global_load_lds((const __attribute__((address_space(1))) void*)g,
                                     (__attribute__((address_space(3))) void*)l, 16, 0, 0);
}

__device__ __forceinline__ f32x4 fmax4(f32x4 a, f32x4 b) {
    f32x4 r;
    r[0] = fmaxf(a[0], b[0]); r[1] = fmaxf(a[1], b[1]);
    r[2] = fmaxf(a[2], b[2]); r[3] = fmaxf(a[3], b[3]);
    return r;
}

// ---------------- Fused prep: W transposes | hidden cvt | bias LUT (one launch) ----------------
// blocks [0,3072): transpose W z=blk/1024; [3072,7168): cvt hidden; [7168,7176): bias LUT.
__global__ __launch_bounds__(256) void prep_kernel(const float* __restrict__ hidden,
                                                   const float* __restrict__ Wq,
                                                   const float* __restrict__ Wk,
                                                   const float* __restrict__ Wv,
                                                   const float* __restrict__ rel_bias,
                                                   unsigned short* __restrict__ hA,
                                                   unsigned short* __restrict__ WTall,
                                                   float* __restrict__ bt) {
    int blk = blockIdx.x;
    int t = threadIdx.x;
    if (blk < 3072) {
        // ---- W [K][N] fp32 -> WT [N][K] bf16, 32x32 tiles ----
        int z = blk >> 10;
        int xy = blk & 1023;
        int bx = xy & 31, by = xy >> 5;
        const float* in = (z == 0) ? Wq : (z == 1) ? Wk : Wv;
        unsigned short* outp = WTall + (size_t)z * 1024 * 1024;
        __shared__ float tile[32][33];
        int tx = t & 31, ty = t >> 5;           // 32 x 8
        int x = bx * 32 + tx;
        int y0 = by * 32;
        #pragma unroll
        for (int j = ty; j < 32; j += 8)
            tile[j][tx] = in[(size_t)(y0 + j) * 1024 + x];
        __syncthreads();
        int ox = y0 + tx;
        int oy0 = bx * 32;
        #pragma unroll
        for (int j = ty; j < 32; j += 8)
            outp[(size_t)(oy0 + j) * 1024 + ox] = f2b(tile[tx][j]);
    } else if (blk < 7168) {
        // ---- hidden fp32 -> bf16, 4 elems/thread ----
        int i = ((blk - 3072) * 256 + t) * 4;
        float4 v = *reinterpret_cast<const float4*>(hidden + i);
        ushort4 o;
        o.x = f2b(v.x); o.y = f2b(v.y); o.z = f2b(v.z); o.w = f2b(v.w);
        *reinterpret_cast<ushort4*>(hA + i) = o;
    } else {
        // ---- T5 bias LUT (pre-scaled by log2e): bt[h][n], n = max(q-k,0) ----
        int n = (blk - 7168) * 256 + t;
        int bucket;
        if (n < 16) {
            bucket = n;
        } else {
            float nf = (float)n;
            int v = 16 + (int)((logf(nf / 16.0f) / 0.69314718f) * 16.0f);
            bucket = v < 31 ? v : 31;
        }
        #pragma unroll
        for (int h = 0; h < 16; ++h)
            bt[(size_t)h * 2048 + n] = rel_bias[bucket * 16 + h] * LOG2E;
    }
}

// ---------------- QKV projection GEMM (m97 structure + XCD chunk swizzle) ----------------
// vt output is PRE-PERMUTED per 32-key chunk so the attn kernel's zero-shuffle PV can
// stage V with plain b128 copies: within chunk, key kk lives at position
// p = ((kk>>2)&3)*8 + ((kk>>4)&1)*4 + (kk&3).
__global__ __launch_bounds__(256) void gemm_qkv_kernel(const unsigned short* __restrict__ A,
                                                       const unsigned short* __restrict__ WTall,
                                                       const float* __restrict__ bq,
                                                       const float* __restrict__ bk,
                                                       const float* __restrict__ bv,
                                                       unsigned short* __restrict__ qws,
                                                       unsigned short* __restrict__ kws,
                                                       unsigned short* __restrict__ vtw) {
    const int K = 1024;
    int p = blockIdx.x;
    int lid = (p & 7) * 96 + (p >> 3);
    int bx = lid & 31;
    int rem = lid >> 5;
    int by = rem & 7;
    int z = rem >> 3;

    const unsigned short* Bm = WTall + (size_t)z * 1024 * 1024;
    const float* bias = (z == 0) ? bq : (z == 1) ? bk : bv;

    __shared__ unsigned short As[128 * 32];
    __shared__ unsigned short Bs[128 * 32];

    int t = threadIdx.x;
    int lane = t & 63, w = t >> 6;
    int wr = w >> 1, wc = w & 1;
    int g = lane >> 4, r = lane & 15;
    int m0 = bx * 128, n0 = by * 128;

    int lrow = lane >> 2;
    int lcol = (lane & 3) * 8;
    const unsigned short* ga0 = A + (size_t)(m0 + w * 32 + lrow) * K + lcol;
    const unsigned short* ga1 = ga0 + 16 * K;
    const unsigned short* gb0 = Bm + (size_t)(n0 + w * 32 + lrow) * K + lcol;
    const unsigned short* gb1 = gb0 + 16 * K;
    unsigned short* lA0 = &As[(w * 32) * 32];
    unsigned short* lA1 = &As[(w * 32 + 16) * 32];
    unsigned short* lB0 = &Bs[(w * 32) * 32];
    unsigned short* lB1 = &Bs[(w * 32 + 16) * 32];

    f32x4 acc[4][4] = {};

    for (int kb = 0; kb < K; kb += 32) {
        gload_lds16(ga0 + kb, lA0);
        gload_lds16(ga1 + kb, lA1);
        gload_lds16(gb0 + kb, lB0);
        gload_lds16(gb1 + kb, lB1);
        __syncthreads();

        bf16x8 af[4], bfr[4];
        #pragma unroll
        for (int i = 0; i < 4; ++i)
            af[i] = *reinterpret_cast<const bf16x8*>(&As[(wr * 64 + i * 16 + r) * 32 + g * 8]);
        #pragma unroll
        for (int j = 0; j < 4; ++j)
            bfr[j] = *reinterpret_cast<const bf16x8*>(&Bs[(wc * 64 + j * 16 + r) * 32 + g * 8]);
        #pragma unroll
        for (int i = 0; i < 4; ++i) {
            #pragma unroll
            for (int j = 0; j < 4; ++j)
                acc[i][j] = MFMA16x16x32(af[i], bfr[j], acc[i][j]);
        }
        __syncthreads();
    }

    if (z < 2) {
        unsigned short* C = (z == 0) ? qws : kws;
        float sc = (z == 0) ? QSCALE : 1.0f;
        #pragma unroll
        for (int j = 0; j < 4; ++j) {
            int n = n0 + wc * 64 + j * 16 + r;
            float bj = bias[n];
            #pragma unroll
            for (int i = 0; i < 4; ++i) {
                int mbase = m0 + wr * 64 + i * 16 + g * 4;
                #pragma unroll
                for (int e = 0; e < 4; ++e)
                    C[(size_t)(mbase + e) * 1024 + n] = f2b((acc[i][j][e] + bj) * sc);
            }
        }
    } else {
        #pragma unroll
        for (int j = 0; j < 4; ++j) {
            int n = n0 + wc * 64 + j * 16 + r;
            int hh = n >> 6, d = n & 63;
            float bj = bias[n];
            #pragma unroll
            for (int i = 0; i < 4; ++i) {
                int mbase = m0 + wr * 64 + i * 16 + g * 4;   // s base (mult of 4)
                int bb = mbase >> 11;
                int kk5 = mbase & 31;
                int pbase = ((kk5 >> 2) & 3) * 8 + ((kk5 >> 4) & 1) * 4;
                int sp = ((mbase & 2047) & ~31) | pbase;     // permuted s within 2048
                ushort4 pk4;
                pk4.x = f2b(acc[i][j][0] + bj);
                pk4.y = f2b(acc[i][j][1] + bj);
                pk4.z = f2b(acc[i][j][2] + bj);
                pk4.w = f2b(acc[i][j][3] + bj);
                *reinterpret_cast<ushort4*>(vtw + ((size_t)((bb * 16 + hh) * 64 + d)) * 2048 + sp) = pk4;
            }
        }
    }
}

// ---------------- Flash attention v7: 32 q-rows/wave, zero-shuffle PV, early ds_write ----------------
// QBLK=128 (4 waves x 32 rows as two 16-row groups sharing K/V fragment reads).
// Grid 512, XCD swizzle. LDS stride 72 (144B rows, 16B-aligned b128).
// Next-tile ds_writes hoisted between softmax and PV: target buffer (cur^1) is free
// since the previous barrier, and the end-of-iter barrier no longer waits on them.
__global__ __launch_bounds__(256, 2) void attn_kernel(const unsigned short* __restrict__ qg,
                                                      const unsigned short* __restrict__ kg,
                                                      const unsigned short* __restrict__ vt,
                                                      const float* __restrict__ bt,
                                                      float* __restrict__ out) {
    int p = blockIdx.x;
    int lid = (p & 7) * 64 + (p >> 3);
    int bh = lid >> 4, qt = lid & 15;
    int b = bh >> 4, h = bh & 15;
    int t = threadIdx.x;
    int lane = t & 63, w = t >> 6;
    int g = lane >> 4, r = lane & 15;

    __shared__ unsigned short Ks[2][64][72];
    __shared__ unsigned short Vs[2][64][72];
    __shared__ float bts[256];

    bts[t] = bt[(size_t)h * 2048 + t];

    int q0 = qt * 128 + w * 32 + r;
    int q1 = q0 + 16;
    const unsigned short* qp0 = qg + ((size_t)(b * 2048 + q0)) * 1024 + h * 64;
    const unsigned short* qp1 = qg + ((size_t)(b * 2048 + q1)) * 1024 + h * 64;
    bf16x8 qa0 = *reinterpret_cast<const bf16x8*>(qp0 + g * 8);
    bf16x8 qb0 = *reinterpret_cast<const bf16x8*>(qp0 + 32 + g * 8);
    bf16x8 qa1 = *reinterpret_cast<const bf16x8*>(qp1 + g * 8);
    bf16x8 qb1 = *reinterpret_cast<const bf16x8*>(qp1 + 32 + g * 8);

    bf16x8 vones;
    #pragma unroll
    for (int j = 0; j < 8; ++j) vones[j] = (short)0x3F80;

    int srow = t >> 3;
    int sce = (t & 7) * 8;
    const unsigned short* kgp = kg + (size_t)(b * 2048 + srow) * 1024 + h * 64 + sce;
    const unsigned short* vgp = vt + ((size_t)(b * 16 + h) * 64 + srow) * 2048 + sce;

    {
        bf16x8 a0 = *reinterpret_cast<const bf16x8*>(kgp);
        bf16x8 a1 = *reinterpret_cast<const bf16x8*>(kgp + 32 * 1024);
        bf16x8 b0 = *reinterpret_cast<const bf16x8*>(vgp);
        bf16x8 b1 = *reinterpret_cast<const bf16x8*>(vgp + 32 * 2048);
        *reinterpret_cast<bf16x8*>(&Ks[0][srow][sce]) = a0;
        *reinterpret_cast<bf16x8*>(&Ks[0][srow + 32][sce]) = a1;
        *reinterpret_cast<bf16x8*>(&Vs[0][srow][sce]) = b0;
        *reinterpret_cast<bf16x8*>(&Vs[0][srow + 32][sce]) = b1;
    }
    kgp += 64 * 1024;
    vgp += 64;
    __syncthreads();

    float b0c = bts[0];      // future tiles: n = 0
    float b31c = bts[31];    // far-past tiles: n >= 31 -> bucket 31

    float mr0 = -1e30f, mr1 = -1e30f;
    f32x4 o0[4] = {}, o1[4] = {};
    f32x4 d0 = {}, d1 = {};

    #pragma unroll 2
    for (int kvi = 0; kvi < 32; ++kvi) {
        int kv = kvi * 64;
        int cur = kvi & 1;
        bool hasnext = kvi < 31;
        bf16x8 nk0, nk1, nv0, nv1;
        if (hasnext) {
            nk0 = *reinterpret_cast<const bf16x8*>(kgp);
            nk1 = *reinterpret_cast<const bf16x8*>(kgp + 32 * 1024);
            nv0 = *reinterpret_cast<const bf16x8*>(vgp);
            nv1 = *reinterpret_cast<const bf16x8*>(vgp + 32 * 2048);
            kgp += 64 * 1024;
            vgp += 64;
        }

        // ---- QK^T (swapped), both groups share K fragments ----
        f32x4 sc0[4], sc1[4];
        __builtin_amdgcn_s_setprio(1);
        #pragma unroll
        for (int kt = 0; kt < 4; ++kt) {
            bf16x8 ka = *reinterpret_cast<const bf16x8*>(&Ks[cur][kt * 16 + r][g * 8]);
            bf16x8 kb2 = *reinterpret_cast<const bf16x8*>(&Ks[cur][kt * 16 + r][32 + g * 8]);
            f32x4 s0 = {}; s0 = MFMA16x16x32(ka, qa0, s0); sc0[kt] = MFMA16x16x32(kb2, qb0, s0);
            f32x4 s1 = {}; s1 = MFMA16x16x32(ka, qa1, s1); sc1[kt] = MFMA16x16x32(kb2, qb1, s1);
        }
        __builtin_amdgcn_s_setprio(0);

        // ---- bias ----
        int dd = 2 * qt - kvi;
        bool slow = (dd >= -1) && (dd <= 1);
        float cb = slow ? 0.f : (dd >= 2 ? b31c : b0c);
        if (slow) {
            #pragma unroll
            for (int kt = 0; kt < 4; ++kt) {
                int nb0 = q0 - (kv + kt * 16 + g * 4);
                int nb1 = nb0 + 16;
                #pragma unroll
                for (int e = 0; e < 4; ++e) {
                    int n0i = nb0 - e; n0i = n0i < 0 ? 0 : n0i;
                    int n1i = nb1 - e; n1i = n1i < 0 ? 0 : n1i;
                    sc0[kt][e] += bts[n0i];
                    sc1[kt][e] += bts[n1i];
                }
            }
        }

        // ---- online softmax per group (defer-max) ----
        union { unsigned u[8]; bf16x8 v2[2]; } pk0, pk1;
        {
            f32x4 mx = fmax4(fmax4(sc0[0], sc0[1]), fmax4(sc0[2], sc0[3]));
            float pmax = fmaxf(fmaxf(mx[0], mx[1]), fmaxf(mx[2], mx[3]));
            pmax = fmaxf(pmax, __shfl_xor(pmax, 16));
            pmax = fmaxf(pmax, __shfl_xor(pmax, 32));
            float pb = pmax + cb;
            if (!__all(pb - mr0 <= 8.0f)) {
                float mnew = fmaxf(mr0, pb);
                float scale = EXP2F(mr0 - mnew);
                float s0 = __shfl(scale, g * 4 + 0);
                float s1 = __shfl(scale, g * 4 + 1);
                float s2 = __shfl(scale, g * 4 + 2);
                float s3 = __shfl(scale, g * 4 + 3);
                #pragma unroll
                for (int nt = 0; nt < 4; ++nt) {
                    o0[nt][0] *= s0; o0[nt][1] *= s1; o0[nt][2] *= s2; o0[nt][3] *= s3;
                }
                d0[0] *= s0; d0[1] *= s1; d0[2] *= s2; d0[3] *= s3;
                mr0 = mnew;
            }
            float moff = mr0 - cb;
            #pragma unroll
            for (int kt = 0; kt < 4; ++kt) {
                float p0 = EXP2F(sc0[kt][0] - moff);
                float p1 = EXP2F(sc0[kt][1] - moff);
                float p2 = EXP2F(sc0[kt][2] - moff);
                float p3 = EXP2F(sc0[kt][3] - moff);
                pk0.u[kt * 2 + 0] = pkbf2(p0, p1);
                pk0.u[kt * 2 + 1] = pkbf2(p2, p3);
            }
        }
        {
            f32x4 mx = fmax4(fmax4(sc1[0], sc1[1]), fmax4(sc1[2], sc1[3]));
            float pmax = fmaxf(fmaxf(mx[0], mx[1]), fmaxf(mx[2], mx[3]));
            pmax = fmaxf(pmax, __shfl_xor(pmax, 16));
            pmax = fmaxf(pmax, __shfl_xor(pmax, 32));
            float pb = pmax + cb;
            if (!__all(pb - mr1 <= 8.0f)) {
                float mnew = fmaxf(mr1, pb);
                float scale = EXP2F(mr1 - mnew);
                float s0 = __shfl(scale, g * 4 + 0);
                float s1 = __shfl(scale, g * 4 + 1);
                float s2 = __shfl(scale, g * 4 + 2);
                float s3 = __shfl(scale, g * 4 + 3);
                #pragma unroll
                for (int nt = 0; nt < 4; ++nt) {
                    o1[nt][0] *= s0; o1[nt][1] *= s1; o1[nt][2] *= s2; o1[nt][3] *= s3;
                }
                d1[0] *= s0; d1[1] *= s1; d1[2] *= s2; d1[3] *= s3;
                mr1 = mnew;
            }
            float moff = mr1 - cb;
            #pragma unroll
            for (int kt = 0; kt < 4; ++kt) {
                float p0 = EXP2F(sc1[kt][0] - moff);
                float p1 = EXP2F(sc1[kt][1] - moff);
                float p2 = EXP2F(sc1[kt][2] - moff);
                float p3 = EXP2F(sc1[kt][3] - moff);
                pk1.u[kt * 2 + 0] = pkbf2(p0, p1);
                pk1.u[kt * 2 + 1] = pkbf2(p2, p3);
            }
        }

        // ---- stage next tile EARLY (cur^1 free since previous barrier); overlaps PV ----
        if (hasnext) {
            *reinterpret_cast<bf16x8*>(&Ks[cur ^ 1][srow][sce]) = nk0;
            *reinterpret_cast<bf16x8*>(&Ks[cur ^ 1][srow + 32][sce]) = nk1;
            *reinterpret_cast<bf16x8*>(&Vs[cur ^ 1][srow][sce]) = nv0;
            *reinterpret_cast<bf16x8*>(&Vs[cur ^ 1][srow + 32][sce]) = nv1;
        }

        // ---- PV + denominators: V fragments shared by both groups ----
        __builtin_amdgcn_s_setprio(1);
        #pragma unroll
        for (int c = 0; c < 2; ++c) {
            bf16x8 pf0 = pk0.v2[c];
            bf16x8 pf1 = pk1.v2[c];
            bf16x8 vf0 = *reinterpret_cast<const bf16x8*>(&Vs[cur][0 * 16 + r][c * 32 + g * 8]);
            bf16x8 vf1 = *reinterpret_cast<const bf16x8*>(&Vs[cur][1 * 16 + r][c * 32 + g * 8]);
            bf16x8 vf2 = *reinterpret_cast<const bf16x8*>(&Vs[cur][2 * 16 + r][c * 32 + g * 8]);
            bf16x8 vf3 = *reinterpret_cast<const bf16x8*>(&Vs[cur][3 * 16 + r][c * 32 + g * 8]);
            o0[0] = MFMA16x16x32(pf0, vf0, o0[0]);
            o1[0] = MFMA16x16x32(pf1, vf0, o1[0]);
            o0[1] = MFMA16x16x32(pf0, vf1, o0[1]);
            o1[1] = MFMA16x16x32(pf1, vf1, o1[1]);
            o0[2] = MFMA16x16x32(pf0, vf2, o0[2]);
            o1[2] = MFMA16x16x32(pf1, vf2, o1[2]);
            o0[3] = MFMA16x16x32(pf0, vf3, o0[3]);
            o1[3] = MFMA16x16x32(pf1, vf3, o1[3]);
            d0 = MFMA16x16x32(pf0, vones, d0);
            d1 = MFMA16x16x32(pf1, vones, d1);
        }
        __builtin_amdgcn_s_setprio(0);

        __syncthreads();
    }

    #pragma unroll
    for (int e = 0; e < 4; ++e) {
        int qr0 = qt * 128 + w * 32 + g * 4 + e;
        float inv0 = 1.0f / d0[e];
        size_t ob0 = ((size_t)(b * 2048 + qr0)) * 1024 + h * 64 + r;
        float inv1 = 1.0f / d1[e];
        size_t ob1 = ob0 + (size_t)16 * 1024;
        #pragma unroll
        for (int nt = 0; nt < 4; ++nt) {
            out[ob0 + nt * 16] = o0[nt][e] * inv0;
            out[ob1 + nt * 16] = o1[nt][e] * inv1;
        }
    }
}

extern "C" void kernel_launch(void* const* d_in, const int* in_sizes, int n_in,
                              void* d_out, int out_size, void* d_ws, size_t ws_size,
                              hipStream_t stream) {
    const float* hidden = (const float*)d_in[0];
    const float* Wq = (const float*)d_in[1];
    const float* bq = (const float*)d_in[2];
    const float* Wk = (const float*)d_in[3];
    const float* bk = (const float*)d_in[4];
    const float* Wv = (const float*)d_in[5];
    const float* bv = (const float*)d_in[6];
    const float* rel_bias = (const float*)d_in[7];
    float* out = (float*)d_out;

    char* ws = (char*)d_ws;
    // ws layout: WT 6MB @0 | q 8MB @6M | k 8MB @14M | vt 16MB @22M | bt 128KB @38M
    unsigned short* WT  = (unsigned short*)(ws);
    unsigned short* qws = (unsigned short*)(ws + (size_t)6 * 1024 * 1024);
    unsigned short* kws = (unsigned short*)(ws + (size_t)14 * 1024 * 1024);
    unsigned short* vtw = (unsigned short*)(ws + (size_t)22 * 1024 * 1024);
    float* bt           = (float*)(ws + (size_t)38 * 1024 * 1024);
    unsigned short* hA  = (unsigned short*)d_out;   // parked; overwritten by attn

    prep_kernel<<<7176, 256, 0, stream>>>(hidden, Wq, Wk, Wv, rel_bias, hA, WT, bt);
    gemm_qkv_kernel<<<768, 256, 0, stream>>>(hA, WT, bq, bk, bv, qws, kws, vtw);
    attn_kernel<<<512, 256, 0, stream>>>(qws, kws, vtw, bt, out);
}

// Round 9
// 175.024 us; speedup vs baseline: 2.0909x; 1.1039x over previous
//
#include <hip/hip_runtime.h>
#include <hip/hip_bf16.h>

typedef __attribute__((ext_vector_type(8))) short bf16x8;
typedef __attribute__((ext_vector_type(4))) float f32x4;

#define MFMA16x16x32(a, b, c) __builtin_amdgcn_mfma_f32_16x16x32_bf16(a, b, c, 0, 0, 0)
#define EXP2F(x) __builtin_amdgcn_exp2f(x)

#define LOG2E 1.44269504f
#define QSCALE (0.125f * 1.44269504f)

__device__ __forceinline__ unsigned short f2b(float x) {
    union { float f; unsigned int u; } v; v.f = x;
    unsigned int r = v.u + 0x7FFFu + ((v.u >> 16) & 1u);
    return (unsigned short)(r >> 16);
}

__device__ __forceinline__ unsigned pkbf2(float a, float b) {
    float2 f; f.x = a; f.y = b;
    __hip_bfloat162 h = __float22bfloat162_rn(f);
    union { __hip_bfloat162 h2; unsigned u; } cv; cv.h2 = h;
    return cv.u;
}

__device__ __forceinline__ void gload_lds16(const unsigned short* g, unsigned short* l) {
    __builtin_amdgcn_global_load_lds((const __attribute__((address_space(1))) void*)g,
                                     (__attribute__((address_space(3))) void*)l, 16, 0, 0);
}

__device__ __forceinline__ f32x4 fmax4(f32x4 a, f32x4 b) {
    f32x4 r;
    r[0] = fmaxf(a[0], b[0]); r[1] = fmaxf(a[1], b[1]);
    r[2] = fmaxf(a[2], b[2]); r[3] = fmaxf(a[3], b[3]);
    return r;
}

// ---------------- Fused prep: W transposes | hidden cvt | bias LUT (one launch) ----------------
__global__ __launch_bounds__(256) void prep_kernel(const float* __restrict__ hidden,
                                                   const float* __restrict__ Wq,
                                                   const float* __restrict__ Wk,
                                                   const float* __restrict__ Wv,
                                                   const float* __restrict__ rel_bias,
                                                   unsigned short* __restrict__ hA,
                                                   unsigned short* __restrict__ WTall,
                                                   float* __restrict__ bt) {
    int blk = blockIdx.x;
    int t = threadIdx.x;
    if (blk < 3072) {
        int z = blk >> 10;
        int xy = blk & 1023;
        int bx = xy & 31, by = xy >> 5;
        const float* in = (z == 0) ? Wq : (z == 1) ? Wk : Wv;
        unsigned short* outp = WTall + (size_t)z * 1024 * 1024;
        __shared__ float tile[32][33];
        int tx = t & 31, ty = t >> 5;
        int x = bx * 32 + tx;
        int y0 = by * 32;
        #pragma unroll
        for (int j = ty; j < 32; j += 8)
            tile[j][tx] = in[(size_t)(y0 + j) * 1024 + x];
        __syncthreads();
        int ox = y0 + tx;
        int oy0 = bx * 32;
        #pragma unroll
        for (int j = ty; j < 32; j += 8)
            outp[(size_t)(oy0 + j) * 1024 + ox] = f2b(tile[tx][j]);
    } else if (blk < 7168) {
        int i = ((blk - 3072) * 256 + t) * 4;
        float4 v = *reinterpret_cast<const float4*>(hidden + i);
        ushort4 o;
        o.x = f2b(v.x); o.y = f2b(v.y); o.z = f2b(v.z); o.w = f2b(v.w);
        *reinterpret_cast<ushort4*>(hA + i) = o;
    } else {
        int n = (blk - 7168) * 256 + t;
        int bucket;
        if (n < 16) {
            bucket = n;
        } else {
            float nf = (float)n;
            int v = 16 + (int)((logf(nf / 16.0f) / 0.69314718f) * 16.0f);
            bucket = v < 31 ? v : 31;
        }
        #pragma unroll
        for (int h = 0; h < 16; ++h)
            bt[(size_t)h * 2048 + n] = rel_bias[bucket * 16 + h] * LOG2E;
    }
}

// ---------------- QKV projection GEMM: BK=64 (half the barriers), XCD chunk swizzle ----------------
// vt output PRE-PERMUTED per 32-key chunk: key kk -> position ((kk>>2)&3)*8 + ((kk>>4)&1)*4 + (kk&3).
__global__ __launch_bounds__(256, 3) void gemm_qkv_kernel(const unsigned short* __restrict__ A,
                                                          const unsigned short* __restrict__ WTall,
                                                          const float* __restrict__ bq,
                                                          const float* __restrict__ bk,
                                                          const float* __restrict__ bv,
                                                          unsigned short* __restrict__ qws,
                                                          unsigned short* __restrict__ kws,
                                                          unsigned short* __restrict__ vtw) {
    const int K = 1024;
    int p = blockIdx.x;
    int lid = (p & 7) * 96 + (p >> 3);
    int bx = lid & 31;
    int rem = lid >> 5;
    int by = rem & 7;
    int z = rem >> 3;

    const unsigned short* Bm = WTall + (size_t)z * 1024 * 1024;
    const float* bias = (z == 0) ? bq : (z == 1) ? bk : bv;

    __shared__ unsigned short As[128 * 64];
    __shared__ unsigned short Bs[128 * 64];

    int t = threadIdx.x;
    int lane = t & 63, w = t >> 6;
    int wr = w >> 1, wc = w & 1;
    int g = lane >> 4, r = lane & 15;
    int m0 = bx * 128, n0 = by * 128;

    // staging: wave w covers rows [w*32, w*32+32); 4 gloads of 8 rows each (128B rows)
    int lrow = lane >> 3;                 // 0..7
    int lcol = (lane & 7) * 8;            // 0..56
    const unsigned short* ga = A + (size_t)(m0 + w * 32 + lrow) * K + lcol;
    const unsigned short* gb = Bm + (size_t)(n0 + w * 32 + lrow) * K + lcol;
    unsigned short* lA = &As[(w * 32) * 64];
    unsigned short* lB = &Bs[(w * 32) * 64];

    f32x4 acc[4][4] = {};

    for (int kb = 0; kb < K; kb += 64) {
        #pragma unroll
        for (int j = 0; j < 4; ++j) {
            gload_lds16(ga + kb + (size_t)(8 * j) * K, lA + (8 * j) * 64);
            gload_lds16(gb + kb + (size_t)(8 * j) * K, lB + (8 * j) * 64);
        }
        __syncthreads();

        #pragma unroll
        for (int half = 0; half < 2; ++half) {
            bf16x8 af[4], bfr[4];
            #pragma unroll
            for (int i = 0; i < 4; ++i)
                af[i] = *reinterpret_cast<const bf16x8*>(&As[(wr * 64 + i * 16 + r) * 64 + half * 32 + g * 8]);
            #pragma unroll
            for (int j = 0; j < 4; ++j)
                bfr[j] = *reinterpret_cast<const bf16x8*>(&Bs[(wc * 64 + j * 16 + r) * 64 + half * 32 + g * 8]);
            #pragma unroll
            for (int i = 0; i < 4; ++i) {
                #pragma unroll
                for (int j = 0; j < 4; ++j)
                    acc[i][j] = MFMA16x16x32(af[i], bfr[j], acc[i][j]);
            }
        }
        __syncthreads();
    }

    if (z < 2) {
        unsigned short* C = (z == 0) ? qws : kws;
        float sc = (z == 0) ? QSCALE : 1.0f;
        #pragma unroll
        for (int j = 0; j < 4; ++j) {
            int n = n0 + wc * 64 + j * 16 + r;
            float bj = bias[n];
            #pragma unroll
            for (int i = 0; i < 4; ++i) {
                int mbase = m0 + wr * 64 + i * 16 + g * 4;
                #pragma unroll
                for (int e = 0; e < 4; ++e)
                    C[(size_t)(mbase + e) * 1024 + n] = f2b((acc[i][j][e] + bj) * sc);
            }
        }
    } else {
        #pragma unroll
        for (int j = 0; j < 4; ++j) {
            int n = n0 + wc * 64 + j * 16 + r;
            int hh = n >> 6, d = n & 63;
            float bj = bias[n];
            #pragma unroll
            for (int i = 0; i < 4; ++i) {
                int mbase = m0 + wr * 64 + i * 16 + g * 4;
                int bb = mbase >> 11;
                int kk5 = mbase & 31;
                int pbase = ((kk5 >> 2) & 3) * 8 + ((kk5 >> 4) & 1) * 4;
                int sp = ((mbase & 2047) & ~31) | pbase;
                ushort4 pk4;
                pk4.x = f2b(acc[i][j][0] + bj);
                pk4.y = f2b(acc[i][j][1] + bj);
                pk4.z = f2b(acc[i][j][2] + bj);
                pk4.w = f2b(acc[i][j][3] + bj);
                *reinterpret_cast<ushort4*>(vtw + ((size_t)((bb * 16 + hh) * 64 + d)) * 2048 + sp) = pk4;
            }
        }
    }
}

// ---------------- Flash attention v8: KVBLK=128, 32 q-rows/wave, zero-shuffle PV ----------------
// 16 iterations of 128 keys; one barrier per iteration. Per-tile softmax fixed costs
// (max-tree, shfl reduce, defer-check) amortized over 2x keys vs v7.
__global__ __launch_bounds__(256, 2) void attn_kernel(const unsigned short* __restrict__ qg,
                                                      const unsigned short* __restrict__ kg,
                                                      const unsigned short* __restrict__ vt,
                                                      const float* __restrict__ bt,
                                                      float* __restrict__ out) {
    int p = blockIdx.x;
    int lid = (p & 7) * 64 + (p >> 3);
    int bh = lid >> 4, qt = lid & 15;
    int b = bh >> 4, h = bh & 15;
    int t = threadIdx.x;
    int lane = t & 63, w = t >> 6;
    int g = lane >> 4, r = lane & 15;

    __shared__ unsigned short Ks[2][128][72];   // [buf][key][d]
    __shared__ unsigned short Vs[2][64][136];   // [buf][d][key-permuted]
    __shared__ float bts[256];

    bts[t] = bt[(size_t)h * 2048 + t];

    int q0 = qt * 128 + w * 32 + r;
    int q1 = q0 + 16;
    const unsigned short* qp0 = qg + ((size_t)(b * 2048 + q0)) * 1024 + h * 64;
    const unsigned short* qp1 = qg + ((size_t)(b * 2048 + q1)) * 1024 + h * 64;
    bf16x8 qa0 = *reinterpret_cast<const bf16x8*>(qp0 + g * 8);
    bf16x8 qb0 = *reinterpret_cast<const bf16x8*>(qp0 + 32 + g * 8);
    bf16x8 qa1 = *reinterpret_cast<const bf16x8*>(qp1 + g * 8);
    bf16x8 qb1 = *reinterpret_cast<const bf16x8*>(qp1 + 32 + g * 8);

    bf16x8 vones;
    #pragma unroll
    for (int j = 0; j < 8; ++j) vones[j] = (short)0x3F80;

    // K staging: thread covers key rows srow+{0,32,64,96}, 8 d-elems at sce
    int srow = t >> 3;                   // 0..31
    int sce = (t & 7) * 8;
    const unsigned short* kgp = kg + (size_t)(b * 2048 + srow) * 1024 + h * 64 + sce;
    // V staging: thread covers d-row vrow, key chunks vc + {0,32,64,96}
    int vrow = t >> 2;                   // 0..63
    int vc = (t & 3) * 8;
    const unsigned short* vgp = vt + ((size_t)(b * 16 + h) * 64 + vrow) * 2048 + vc;

    {
        #pragma unroll
        for (int j = 0; j < 4; ++j) {
            bf16x8 a = *reinterpret_cast<const bf16x8*>(kgp + (size_t)(32 * j) * 1024);
            *reinterpret_cast<bf16x8*>(&Ks[0][srow + 32 * j][sce]) = a;
            bf16x8 v = *reinterpret_cast<const bf16x8*>(vgp + 32 * j);
            *reinterpret_cast<bf16x8*>(&Vs[0][vrow][vc + 32 * j]) = v;
        }
    }
    kgp += 128 * 1024;
    vgp += 128;
    __syncthreads();

    float b0c = bts[0];
    float b31c = bts[31];

    float mr0 = -1e30f, mr1 = -1e30f;
    f32x4 o0[4] = {}, o1[4] = {};
    f32x4 d0 = {}, d1 = {};

    #pragma unroll 2
    for (int kvi = 0; kvi < 16; ++kvi) {
        int cur = kvi & 1;
        bool hasnext = kvi < 15;
        bf16x8 nk[4], nv[4];
        if (hasnext) {
            #pragma unroll
            for (int j = 0; j < 4; ++j) {
                nk[j] = *reinterpret_cast<const bf16x8*>(kgp + (size_t)(32 * j) * 1024);
                nv[j] = *reinterpret_cast<const bf16x8*>(vgp + 32 * j);
            }
            kgp += 128 * 1024;
            vgp += 128;
        }

        // ---- QK^T (swapped): 8 kt sub-tiles of 16 keys ----
        f32x4 sc0[8], sc1[8];
        __builtin_amdgcn_s_setprio(1);
        #pragma unroll
        for (int kt = 0; kt < 8; ++kt) {
            bf16x8 ka = *reinterpret_cast<const bf16x8*>(&Ks[cur][kt * 16 + r][g * 8]);
            bf16x8 kb2 = *reinterpret_cast<const bf16x8*>(&Ks[cur][kt * 16 + r][32 + g * 8]);
            f32x4 s0 = {}; s0 = MFMA16x16x32(ka, qa0, s0); sc0[kt] = MFMA16x16x32(kb2, qb0, s0);
            f32x4 s1 = {}; s1 = MFMA16x16x32(ka, qa1, s1); sc1[kt] = MFMA16x16x32(kb2, qb1, s1);
        }
        __builtin_amdgcn_s_setprio(0);

        // ---- bias ----
        int dd = qt - kvi;
        bool slow = (dd == 0) || (dd == 1);
        float cb = slow ? 0.f : (dd >= 2 ? b31c : b0c);
        if (slow) {
            #pragma unroll
            for (int kt = 0; kt < 8; ++kt) {
                int nb0 = q0 - (kvi * 128 + kt * 16 + g * 4);
                int nb1 = nb0 + 16;
                #pragma unroll
                for (int e = 0; e < 4; ++e) {
                    int n0i = nb0 - e; n0i = n0i < 0 ? 0 : n0i;
                    int n1i = nb1 - e; n1i = n1i < 0 ? 0 : n1i;
                    sc0[kt][e] += bts[n0i];
                    sc1[kt][e] += bts[n1i];
                }
            }
        }

        // ---- online softmax per group (defer-max) ----
        union { unsigned u[16]; bf16x8 v2[4]; } pk0, pk1;
        {
            f32x4 mx = fmax4(fmax4(fmax4(sc0[0], sc0[1]), fmax4(sc0[2], sc0[3])),
                             fmax4(fmax4(sc0[4], sc0[5]), fmax4(sc0[6], sc0[7])));
            float pmax = fmaxf(fmaxf(mx[0], mx[1]), fmaxf(mx[2], mx[3]));
            pmax = fmaxf(pmax, __shfl_xor(pmax, 16));
            pmax = fmaxf(pmax, __shfl_xor(pmax, 32));
            float pb = pmax + cb;
            if (!__all(pb - mr0 <= 8.0f)) {
                float mnew = fmaxf(mr0, pb);
                float scale = EXP2F(mr0 - mnew);
                float s0 = __shfl(scale, g * 4 + 0);
                float s1 = __shfl(scale, g * 4 + 1);
                float s2 = __shfl(scale, g * 4 + 2);
                float s3 = __shfl(scale, g * 4 + 3);
                #pragma unroll
                for (int nt = 0; nt < 4; ++nt) {
                    o0[nt][0] *= s0; o0[nt][1] *= s1; o0[nt][2] *= s2; o0[nt][3] *= s3;
                }
                d0[0] *= s0; d0[1] *= s1; d0[2] *= s2; d0[3] *= s3;
                mr0 = mnew;
            }
            float moff = mr0 - cb;
            #pragma unroll
            for (int kt = 0; kt < 8; ++kt) {
                float p0 = EXP2F(sc0[kt][0] - moff);
                float p1 = EXP2F(sc0[kt][1] - moff);
                float p2 = EXP2F(sc0[kt][2] - moff);
                float p3 = EXP2F(sc0[kt][3] - moff);
                pk0.u[kt * 2 + 0] = pkbf2(p0, p1);
                pk0.u[kt * 2 + 1] = pkbf2(p2, p3);
            }
        }
        {
            f32x4 mx = fmax4(fmax4(fmax4(sc1[0], sc1[1]), fmax4(sc1[2], sc1[3])),
                             fmax4(fmax4(sc1[4], sc1[5]), fmax4(sc1[6], sc1[7])));
            float pmax = fmaxf(fmaxf(mx[0], mx[1]), fmaxf(mx[2], mx[3]));
            pmax = fmaxf(pmax, __shfl_xor(pmax, 16));
            pmax = fmaxf(pmax, __shfl_xor(pmax, 32));
            float pb = pmax + cb;
            if (!__all(pb - mr1 <= 8.0f)) {
                float mnew = fmaxf(mr1, pb);
                float scale = EXP2F(mr1 - mnew);
                float s0 = __shfl(scale, g * 4 + 0);
                float s1 = __shfl(scale, g * 4 + 1);
                float s2 = __shfl(scale, g * 4 + 2);
                float s3 = __shfl(scale, g * 4 + 3);
                #pragma unroll
                for (int nt = 0; nt < 4; ++nt) {
                    o1[nt][0] *= s0; o1[nt][1] *= s1; o1[nt][2] *= s2; o1[nt][3] *= s3;
                }
                d1[0] *= s0; d1[1] *= s1; d1[2] *= s2; d1[3] *= s3;
                mr1 = mnew;
            }
            float moff = mr1 - cb;
            #pragma unroll
            for (int kt = 0; kt < 8; ++kt) {
                float p0 = EXP2F(sc1[kt][0] - moff);
                float p1 = EXP2F(sc1[kt][1] - moff);
                float p2 = EXP2F(sc1[kt][2] - moff);
                float p3 = EXP2F(sc1[kt][3] - moff);
                pk1.u[kt * 2 + 0] = pkbf2(p0, p1);
                pk1.u[kt * 2 + 1] = pkbf2(p2, p3);
            }
        }

        // ---- stage next tile (cur^1 free since previous barrier) ----
        if (hasnext) {
            #pragma unroll
            for (int j = 0; j < 4; ++j) {
                *reinterpret_cast<bf16x8*>(&Ks[cur ^ 1][srow + 32 * j][sce]) = nk[j];
                *reinterpret_cast<bf16x8*>(&Vs[cur ^ 1][vrow][vc + 32 * j]) = nv[j];
            }
        }

        // ---- PV + denominators over 4 chunks of 32 keys ----
        __builtin_amdgcn_s_setprio(1);
        #pragma unroll
        for (int c = 0; c < 4; ++c) {
            bf16x8 pf0 = pk0.v2[c];
            bf16x8 pf1 = pk1.v2[c];
            bf16x8 vf0 = *reinterpret_cast<const bf16x8*>(&Vs[cur][0 * 16 + r][c * 32 + g * 8]);
            bf16x8 vf1 = *reinterpret_cast<const bf16x8*>(&Vs[cur][1 * 16 + r][c * 32 + g * 8]);
            bf16x8 vf2 = *reinterpret_cast<const bf16x8*>(&Vs[cur][2 * 16 + r][c * 32 + g * 8]);
            bf16x8 vf3 = *reinterpret_cast<const bf16x8*>(&Vs[cur][3 * 16 + r][c * 32 + g * 8]);
            o0[0] = MFMA16x16x32(pf0, vf0, o0[0]);
            o1[0] = MFMA16x16x32(pf1, vf0, o1[0]);
            o0[1] = MFMA16x16x32(pf0, vf1, o0[1]);
            o1[1] = MFMA16x16x32(pf1, vf1, o1[1]);
            o0[2] = MFMA16x16x32(pf0, vf2, o0[2]);
            o1[2] = MFMA16x16x32(pf1, vf2, o1[2]);
            o0[3] = MFMA16x16x32(pf0, vf3, o0[3]);
            o1[3] = MFMA16x16x32(pf1, vf3, o1[3]);
            d0 = MFMA16x16x32(pf0, vones, d0);
            d1 = MFMA16x16x32(pf1, vones, d1);
        }
        __builtin_amdgcn_s_setprio(0);

        __syncthreads();
    }

    #pragma unroll
    for (int e = 0; e < 4; ++e) {
        int qr0 = qt * 128 + w * 32 + g * 4 + e;
        float inv0 = 1.0f / d0[e];
        size_t ob0 = ((size_t)(b * 2048 + qr0)) * 1024 + h * 64 + r;
        float inv1 = 1.0f / d1[e];
        size_t ob1 = ob0 + (size_t)16 * 1024;
        #pragma unroll
        for (int nt = 0; nt < 4; ++nt) {
            out[ob0 + nt * 16] = o0[nt][e] * inv0;
            out[ob1 + nt * 16] = o1[nt][e] * inv1;
        }
    }
}

extern "C" void kernel_launch(void* const* d_in, const int* in_sizes, int n_in,
                              void* d_out, int out_size, void* d_ws, size_t ws_size,
                              hipStream_t stream) {
    const float* hidden = (const float*)d_in[0];
    const float* Wq = (const float*)d_in[1];
    const float* bq = (const float*)d_in[2];
    const float* Wk = (const float*)d_in[3];
    const float* bk = (const float*)d_in[4];
    const float* Wv = (const float*)d_in[5];
    const float* bv = (const float*)d_in[6];
    const float* rel_bias = (const float*)d_in[7];
    float* out = (float*)d_out;

    char* ws = (char*)d_ws;
    // ws layout: WT 6MB @0 | q 8MB @6M | k 8MB @14M | vt 16MB @22M | bt 128KB @38M
    unsigned short* WT  = (unsigned short*)(ws);
    unsigned short* qws = (unsigned short*)(ws + (size_t)6 * 1024 * 1024);
    unsigned short* kws = (unsigned short*)(ws + (size_t)14 * 1024 * 1024);
    unsigned short* vtw = (unsigned short*)(ws + (size_t)22 * 1024 * 1024);
    float* bt           = (float*)(ws + (size_t)38 * 1024 * 1024);
    unsigned short* hA  = (unsigned short*)d_out;   // parked; overwritten by attn

    prep_kernel<<<7176, 256, 0, stream>>>(hidden, Wq, Wk, Wv, rel_bias, hA, WT, bt);
    gemm_qkv_kernel<<<768, 256, 0, stream>>>(hA, WT, bq, bk, bv, qws, kws, vtw);
    attn_kernel<<<512, 256, 0, stream>>>(qws, kws, vtw, bt, out);
}